// Round 5
// baseline (848.332 us; speedup 1.0000x reference)
//
#include <hip/hip_runtime.h>

// EGNN layer (round 5): persistent 16-wave edge kernel.
//  - edge_k: 1024 threads/block, e_w2t + c_w1t loaded into LDS ONCE per block,
//    grid-stride over 256-edge tiles (wave = one 16x128 MFMA stripe). 2 barriers
//    per 256 edges (was 3 per 64) and no per-tile weight reloads.
//    LDS = 141,312 B -> 1 block/CU = 16 waves/CU (was ~10.7).
//  - prep_k: pa = h@W1a + e_b1, pb = h@W1b (bf16), exploits layer-1 linearity.
//  - agg/coord_agg accumulate in d_out (f32 atomics); node_k finishes in place.
//  - ws = pa + pb + cnt + wt = 26.03 MB.

#define NN 50000
#define NE 800000
#define LDST 136

typedef __bf16 bf16_t;
typedef __bf16 bf16x8 __attribute__((ext_vector_type(8)));
typedef float f32x4 __attribute__((ext_vector_type(4)));

__device__ __forceinline__ float siluf(float v) { return v / (1.f + __expf(-v)); }

// One wave computes a 16-row x 128-col C stripe: C += A(16x128) @ B(128x128).
__device__ __forceinline__ void gemm_stripe(const bf16_t* Arow, const bf16_t* Bcol,
                                            int koff, f32x4 acc[8]) {
#pragma unroll
  for (int ks = 0; ks < 4; ++ks) {
    bf16x8 a = *(const bf16x8*)(Arow + ks * 32 + koff);
#pragma unroll
    for (int nt = 0; nt < 8; ++nt) {
      bf16x8 b = *(const bf16x8*)(Bcol + nt * 16 * LDST + ks * 32 + koff);
      acc[nt] = __builtin_amdgcn_mfma_f32_16x16x32_bf16(a, b, acc[nt], 0, 0, 0);
    }
  }
}

__device__ __forceinline__ void load_B(bf16_t* Bsb, const bf16_t* __restrict__ src, int t) {
  for (int i = t; i < 2048; i += 256) {
    int n = i >> 4, cc = i & 15;
    *(bf16x8*)(Bsb + n * LDST + cc * 8) = *(const bf16x8*)(src + n * 128 + cc * 8);
  }
}

__device__ __forceinline__ bf16x8 cvt8(float4 u0, float4 u1) {
  bf16x8 v;
  v[0] = (bf16_t)u0.x; v[1] = (bf16_t)u0.y; v[2] = (bf16_t)u0.z; v[3] = (bf16_t)u0.w;
  v[4] = (bf16_t)u1.x; v[5] = (bf16_t)u1.y; v[6] = (bf16_t)u1.z; v[7] = (bf16_t)u1.w;
  return v;
}

// ---- transpose 7 128x128 f32 weight blocks into bf16 wt ([n][k] layout) ----
// slots: 0 W1a_t, 1 W1b_t, 2 e_w2t, 3 n_w1a_t, 4 n_w1b_t, 5 n_w2t, 6 c_w1t
__global__ __launch_bounds__(256) void transpose_k(
    const float* __restrict__ e_w1, const float* __restrict__ e_w2,
    const float* __restrict__ n_w1, const float* __restrict__ n_w2,
    const float* __restrict__ c_w1, bf16_t* __restrict__ wt) {
  int b = blockIdx.x;
  const float* src;
  switch (b) {
    case 0: src = e_w1; break;
    case 1: src = e_w1 + 16384; break;
    case 2: src = e_w2; break;
    case 3: src = n_w1; break;
    case 4: src = n_w1 + 16384; break;
    case 5: src = n_w2; break;
    default: src = c_w1; break;
  }
  bf16_t* dst = wt + b * 16384;
  for (int i = threadIdx.x; i < 16384; i += 256) {
    int k = i >> 7, n = i & 127;
    dst[n * 128 + k] = (bf16_t)src[k * 128 + n];
  }
}

// ---- prep: pa = bf16(h@W1a + e_b1), pb = bf16(h@W1b) ----
__global__ __launch_bounds__(256) void prep_k(
    const float* __restrict__ h, const bf16_t* __restrict__ wt,
    const float* __restrict__ e_b1, bf16_t* __restrict__ pa, bf16_t* __restrict__ pb) {
  __shared__ __align__(16) bf16_t Asb[64 * LDST];
  __shared__ __align__(16) bf16_t Bsb[128 * LDST];
  int t = threadIdx.x;
  int node0 = blockIdx.x * 64;
  for (int i = t; i < 1024; i += 256) {
    int rowl = i >> 4, cc = i & 15;
    int node = node0 + rowl; if (node >= NN) node = NN - 1;
    const float4* p = (const float4*)(h + (size_t)node * 128 + cc * 8);
    *(bf16x8*)(Asb + rowl * LDST + cc * 8) = cvt8(p[0], p[1]);
  }
  int lane = t & 63, w = t >> 6;
  int m0 = w * 16, quad = lane >> 4, cix = lane & 15, koff = quad * 8;
  const bf16_t* Arow = Asb + (m0 + cix) * LDST;
  const bf16_t* Bcol = Bsb + cix * LDST;

  bf16_t* outp[2] = {pa, pb};
#pragma unroll
  for (int p = 0; p < 2; ++p) {
    __syncthreads();
    load_B(Bsb, wt + p * 16384, t);
    __syncthreads();
    f32x4 acc[8];
#pragma unroll
    for (int i = 0; i < 8; ++i) acc[i] = (f32x4){0.f, 0.f, 0.f, 0.f};
    gemm_stripe(Arow, Bcol, koff, acc);
#pragma unroll
    for (int nt = 0; nt < 8; ++nt) {
      int colg = nt * 16 + cix;
      float bv = p == 0 ? e_b1[colg] : 0.f;
#pragma unroll
      for (int rix = 0; rix < 4; ++rix) {
        int node = node0 + m0 + quad * 4 + rix;
        if (node < NN) outp[p][(size_t)node * 128 + colg] = (bf16_t)(acc[nt][rix] + bv);
      }
    }
  }
}

// ---- edge kernel: persistent, 1024 threads, 256-edge tiles ----
__global__ __launch_bounds__(1024, 4) void edge_k(
    const bf16_t* __restrict__ pa, const bf16_t* __restrict__ pb,
    const int* __restrict__ ei, const float* __restrict__ eattr,
    const float* __restrict__ x, const bf16_t* __restrict__ wt,
    const float* __restrict__ e_w1, const float* __restrict__ e_b2,
    const float* __restrict__ c_b1, const float* __restrict__ c_w2,
    const float* __restrict__ a_w, const float* __restrict__ a_b,
    float* __restrict__ agg, float* __restrict__ coord_agg, float* __restrict__ cnt) {
  __shared__ __align__(16) bf16_t Bs2[128 * LDST];  // e_w2t,  34816 B
  __shared__ __align__(16) bf16_t Bs6[128 * LDST];  // c_w1t,  34816 B
  __shared__ __align__(16) bf16_t Ag[256 * LDST];   // m tile, 69632 B
  __shared__ int rows_s[256];
  __shared__ int cols_s[256];                       // total 141,312 B

  int t = threadIdx.x;

  // one-time weight loads
  for (int i = t; i < 2048; i += 1024) {
    int n = i >> 4, cc = i & 15;
    *(bf16x8*)(Bs2 + n * LDST + cc * 8) = *(const bf16x8*)(wt + 2 * 16384 + n * 128 + cc * 8);
    *(bf16x8*)(Bs6 + n * LDST + cc * 8) = *(const bf16x8*)(wt + 6 * 16384 + n * 128 + cc * 8);
  }
  __syncthreads();

  int lane = t & 63, w = t >> 6;
  int quad = lane >> 4, cix = lane & 15, koff = quad * 8;
  const bf16_t* B2col = Bs2 + cix * LDST;
  const bf16_t* B6col = Bs6 + cix * LDST;
  const float* wrp = e_w1 + 256 * 128;
  const float* wep = e_w1 + 257 * 128;
  float a_bv = a_b[0];

  for (int tile = blockIdx.x; tile < NE / 256; tile += gridDim.x) {
    int e0 = tile * 256;
    int el = w * 16 + cix;  // tile-local edge this lane feeds as A-row m=cix
    int eg = e0 + el;
    int r = ei[eg], c = ei[NE + eg];
    if (quad == 0) { rows_s[el] = r; cols_s[el] = c; }
    float d0 = x[r * 3 + 0] - x[c * 3 + 0];
    float d1 = x[r * 3 + 1] - x[c * 3 + 1];
    float d2 = x[r * 3 + 2] - x[c * 3 + 2];
    float rad = d0 * d0 + d1 * d1 + d2 * d2;
    float ea = eattr[eg];
    const bf16_t* par = pa + (size_t)r * 128;
    const bf16_t* pbr = pb + (size_t)c * 128;

    // GEMM1 fused: z1 built in-register as A-fragment, C = z1 @ e_w2
    f32x4 acc[8];
#pragma unroll
    for (int i = 0; i < 8; ++i) acc[i] = (f32x4){0.f, 0.f, 0.f, 0.f};
#pragma unroll
    for (int ks = 0; ks < 4; ++ks) {
      int kk = ks * 32 + koff;
      bf16x8 pa8 = *(const bf16x8*)(par + kk);
      bf16x8 pb8 = *(const bf16x8*)(pbr + kk);
      float4 wr0 = *(const float4*)(wrp + kk);
      float4 wr1 = *(const float4*)(wrp + kk + 4);
      float4 we0 = *(const float4*)(wep + kk);
      float4 we1 = *(const float4*)(wep + kk + 4);
      float wrv[8] = {wr0.x, wr0.y, wr0.z, wr0.w, wr1.x, wr1.y, wr1.z, wr1.w};
      float wev[8] = {we0.x, we0.y, we0.z, we0.w, we1.x, we1.y, we1.z, we1.w};
      bf16x8 af;
#pragma unroll
      for (int j = 0; j < 8; ++j) {
        float z = (float)pa8[j] + (float)pb8[j] + rad * wrv[j] + ea * wev[j];
        af[j] = (bf16_t)siluf(z);
      }
#pragma unroll
      for (int nt = 0; nt < 8; ++nt) {
        bf16x8 b = *(const bf16x8*)(B2col + nt * 16 * LDST + kk);
        acc[nt] = __builtin_amdgcn_mfma_f32_16x16x32_bf16(af, b, acc[nt], 0, 0, 0);
      }
    }

    // m = silu(. + b2); att = sigmoid(m . a_w + a_b); m *= att; m -> Ag (bf16)
    float attp[4] = {0.f, 0.f, 0.f, 0.f};
#pragma unroll
    for (int nt = 0; nt < 8; ++nt) {
      int colg = nt * 16 + cix;
      float b2v = e_b2[colg];
      float awv = a_w[colg];
#pragma unroll
      for (int rix = 0; rix < 4; ++rix) {
        float v = siluf(acc[nt][rix] + b2v);
        acc[nt][rix] = v;
        attp[rix] += v * awv;
      }
    }
    float attv[4];
#pragma unroll
    for (int rix = 0; rix < 4; ++rix) {
      float s = attp[rix];
      s += __shfl_xor(s, 1); s += __shfl_xor(s, 2);
      s += __shfl_xor(s, 4); s += __shfl_xor(s, 8);
      attv[rix] = 1.f / (1.f + __expf(-(s + a_bv)));
    }
#pragma unroll
    for (int nt = 0; nt < 8; ++nt) {
#pragma unroll
      for (int rix = 0; rix < 4; ++rix) {
        float v = acc[nt][rix] * attv[rix];
        Ag[(w * 16 + quad * 4 + rix) * LDST + nt * 16 + cix] = (bf16_t)v;
      }
    }

    __syncthreads();  // [1] all m rows + rows_s/cols_s visible

    // GEMM2: coord_update = silu(m @ c_w1 + c_b1) . c_w2
    const bf16_t* Arow = Ag + (w * 16 + cix) * LDST;
#pragma unroll
    for (int i = 0; i < 8; ++i) acc[i] = (f32x4){0.f, 0.f, 0.f, 0.f};
    gemm_stripe(Arow, B6col, koff, acc);

    float cup[4] = {0.f, 0.f, 0.f, 0.f};
#pragma unroll
    for (int nt = 0; nt < 8; ++nt) {
      int colg = nt * 16 + cix;
      float cb1v = c_b1[colg];
      float cw2v = c_w2[colg];
#pragma unroll
      for (int rix = 0; rix < 4; ++rix) {
        cup[rix] += siluf(acc[nt][rix] + cb1v) * cw2v;
      }
    }
#pragma unroll
    for (int rix = 0; rix < 4; ++rix) {
      float s = cup[rix];
      s += __shfl_xor(s, 1); s += __shfl_xor(s, 2);
      s += __shfl_xor(s, 4); s += __shfl_xor(s, 8);
      cup[rix] = s;
    }
    if (cix == 0) {
#pragma unroll
      for (int rix = 0; rix < 4; ++rix) {
        int ee = w * 16 + quad * 4 + rix;
        int rr = rows_s[ee], cc = cols_s[ee];
        float cu = cup[rix];
#pragma unroll
        for (int d = 0; d < 3; ++d) {
          float cd = x[rr * 3 + d] - x[cc * 3 + d];
          atomicAdd(&coord_agg[rr * 3 + d], cd * cu);
        }
        atomicAdd(&cnt[rr], 1.0f);
      }
    }

    // scatter gated m into agg (f32 atomics): 256 edges x 128 / 1024 thr = 32/thr
#pragma unroll
    for (int it = 0; it < 32; ++it) {
      int idx = it * 1024 + t;
      int ee = idx >> 7, f = idx & 127;
      float v = (float)Ag[ee * LDST + f];
      atomicAdd(&agg[(size_t)rows_s[ee] * 128 + f], v);
    }

    __syncthreads();  // [2] Ag/rows_s consumed; safe to overwrite next tile
  }
}

// ---- node kernel (in-place on d_out) ----
__global__ __launch_bounds__(256) void node_k(
    const float* __restrict__ h, const float* __restrict__ x,
    const bf16_t* __restrict__ wt, const float* __restrict__ n_b1,
    const float* __restrict__ n_b2, const float* __restrict__ cnt,
    float* __restrict__ out) {
  __shared__ __align__(16) bf16_t Asb[64 * LDST];
  __shared__ __align__(16) bf16_t Bsb[128 * LDST];
  int t = threadIdx.x;
  int node0 = blockIdx.x * 64;
  const float* agg = out;                // accumulated by edge_k
  float* xout = out + (size_t)NN * 128;  // holds coord_agg on entry

  if (t < 192) {
    int node = node0 + t / 3;
    int d = t - (t / 3) * 3;
    if (node < NN) {
      float c = cnt[node];
      float denom = c > 1.f ? c : 1.f;
      float xo = x[node * 3 + d] + xout[node * 3 + d] / denom;
      xout[node * 3 + d] = xo;
    }
  }

  for (int i = t; i < 1024; i += 256) {
    int rowl = i >> 4, cc = i & 15;
    int node = node0 + rowl; if (node >= NN) node = NN - 1;
    const float4* p = (const float4*)(h + (size_t)node * 128 + cc * 8);
    *(bf16x8*)(Asb + rowl * LDST + cc * 8) = cvt8(p[0], p[1]);
  }
  load_B(Bsb, wt + 3 * 16384, t);  // n_w1a_t
  __syncthreads();

  int lane = t & 63, w = t >> 6;
  int m0 = w * 16, quad = lane >> 4, cix = lane & 15, koff = quad * 8;
  const bf16_t* Arow = Asb + (m0 + cix) * LDST;
  const bf16_t* Bcol = Bsb + cix * LDST;

  f32x4 acc[8];
#pragma unroll
  for (int i = 0; i < 8; ++i) acc[i] = (f32x4){0.f, 0.f, 0.f, 0.f};
  gemm_stripe(Arow, Bcol, koff, acc);  // h @ n_w1a

  __syncthreads();

  for (int i = t; i < 1024; i += 256) {
    int rowl = i >> 4, cc = i & 15;
    int node = node0 + rowl; if (node >= NN) node = NN - 1;
    const float4* p = (const float4*)(agg + (size_t)node * 128 + cc * 8);
    *(bf16x8*)(Asb + rowl * LDST + cc * 8) = cvt8(p[0], p[1]);
  }
  load_B(Bsb, wt + 4 * 16384, t);  // n_w1b_t
  __syncthreads();
  gemm_stripe(Arow, Bcol, koff, acc);  // += agg @ n_w1b

#pragma unroll
  for (int nt = 0; nt < 8; ++nt) {
    int colg = nt * 16 + cix;
    float b1v = n_b1[colg];
#pragma unroll
    for (int rix = 0; rix < 4; ++rix) {
      float u = siluf(acc[nt][rix] + b1v);
      Asb[(m0 + quad * 4 + rix) * LDST + colg] = (bf16_t)u;
    }
  }
  __syncthreads();
  load_B(Bsb, wt + 5 * 16384, t);  // n_w2t
  __syncthreads();

#pragma unroll
  for (int i = 0; i < 8; ++i) acc[i] = (f32x4){0.f, 0.f, 0.f, 0.f};
  gemm_stripe(Arow, Bcol, koff, acc);  // u @ n_w2

#pragma unroll
  for (int nt = 0; nt < 8; ++nt) {
    int colg = nt * 16 + cix;
    float b2v = n_b2[colg];
#pragma unroll
    for (int rix = 0; rix < 4; ++rix) {
      int node = node0 + m0 + quad * 4 + rix;
      if (node < NN) {
        float ho = h[(size_t)node * 128 + colg] + acc[nt][rix] + b2v;
        out[(size_t)node * 128 + colg] = ho;
      }
    }
  }
}

extern "C" void kernel_launch(void* const* d_in, const int* in_sizes, int n_in,
                              void* d_out, int out_size, void* d_ws, size_t ws_size,
                              hipStream_t stream) {
  const float* h = (const float*)d_in[0];
  const float* x = (const float*)d_in[1];
  const int* ei = (const int*)d_in[2];
  const float* eattr = (const float*)d_in[3];
  const float* e_w1 = (const float*)d_in[4];
  const float* e_b1 = (const float*)d_in[5];
  const float* e_w2 = (const float*)d_in[6];
  const float* e_b2 = (const float*)d_in[7];
  const float* n_w1 = (const float*)d_in[8];
  const float* n_b1 = (const float*)d_in[9];
  const float* n_w2 = (const float*)d_in[10];
  const float* n_b2 = (const float*)d_in[11];
  const float* c_w1 = (const float*)d_in[12];
  const float* c_b1 = (const float*)d_in[13];
  const float* c_w2 = (const float*)d_in[14];
  const float* a_w = (const float*)d_in[15];
  const float* a_b = (const float*)d_in[16];

  float* outp = (float*)d_out;
  float* agg = outp;                           // N*128 f32 (h_out region)
  float* coord_agg = outp + (size_t)NN * 128;  // N*3 f32 (x_out region)

  // ws layout: pa 12.8MB | pb 12.8MB | cnt 200KB | wt 229KB = 26.03 MB total
  char* ws = (char*)d_ws;
  bf16_t* pa = (bf16_t*)(ws + 0);
  bf16_t* pb = (bf16_t*)(ws + 12800000);
  float* cnt = (float*)(ws + 25600000);
  bf16_t* wt = (bf16_t*)(ws + 25800000);

  hipMemsetAsync(d_out, 0, (size_t)(NN * 131) * 4, stream);
  hipMemsetAsync(ws + 25600000, 0, 200000, stream);
  transpose_k<<<7, 256, 0, stream>>>(e_w1, e_w2, n_w1, n_w2, c_w1, wt);
  prep_k<<<(NN + 63) / 64, 256, 0, stream>>>(h, wt, e_b1, pa, pb);
  edge_k<<<512, 1024, 0, stream>>>(pa, pb, ei, eattr, x, wt, e_w1, e_b2, c_b1,
                                   c_w2, a_w, a_b, agg, coord_agg, cnt);
  node_k<<<(NN + 63) / 64, 256, 0, stream>>>(h, x, wt, n_b1, n_b2, cnt, outp);
}

// Round 6
// 756.394 us; speedup vs baseline: 1.1215x; 1.1215x over previous
//
#include <hip/hip_runtime.h>

// EGNN layer (round 6): ZERO-BARRIER persistent edge kernel.
//  - Round-5 lesson: 1 block/CU + per-tile __syncthreads => whole-CU stalls (no
//    co-resident block to fill barrier gaps). Fix: remove barriers, not add waves.
//  - edge_k: both e_w2 and c_w1 stay LDS-resident for the whole kernel in an
//    unpadded MFMA-chunk layout (lane fragment chunks contiguous: a wave's
//    ds_read_b128 covers 1KB sequential -> conflict-free; 32KB/matrix).
//    Each wave owns a private 16x136 Ag stripe: m C->A round-trip and the agg
//    scatter are wave-local (in-order LDS, no __syncthreads). One barrier total.
//  - 1024 thr/block, 16 indep waves grid-striding 16-edge stripes; LDS 135KB.
//  - prep_k: pa = h@W1a + e_b1, pb = h@W1b (bf16) via layer-1 linearity.
//  - agg/coord_agg accumulate in d_out (f32 atomics); node_k finishes in place.

#define NN 50000
#define NE 800000
#define LDST 136
#define NW 16  // waves per edge_k block

typedef __bf16 bf16_t;
typedef __bf16 bf16x8 __attribute__((ext_vector_type(8)));
typedef float f32x4 __attribute__((ext_vector_type(4)));

__device__ __forceinline__ float siluf(float v) { return v / (1.f + __expf(-v)); }

// One wave computes a 16-row x 128-col C stripe (padded-row LDS variant).
__device__ __forceinline__ void gemm_stripe(const bf16_t* Arow, const bf16_t* Bcol,
                                            int koff, f32x4 acc[8]) {
#pragma unroll
  for (int ks = 0; ks < 4; ++ks) {
    bf16x8 a = *(const bf16x8*)(Arow + ks * 32 + koff);
#pragma unroll
    for (int nt = 0; nt < 8; ++nt) {
      bf16x8 b = *(const bf16x8*)(Bcol + nt * 16 * LDST + ks * 32 + koff);
      acc[nt] = __builtin_amdgcn_mfma_f32_16x16x32_bf16(a, b, acc[nt], 0, 0, 0);
    }
  }
}

__device__ __forceinline__ void load_B(bf16_t* Bsb, const bf16_t* __restrict__ src, int t) {
  for (int i = t; i < 2048; i += 256) {
    int n = i >> 4, cc = i & 15;
    *(bf16x8*)(Bsb + n * LDST + cc * 8) = *(const bf16x8*)(src + n * 128 + cc * 8);
  }
}

__device__ __forceinline__ bf16x8 cvt8(float4 u0, float4 u1) {
  bf16x8 v;
  v[0] = (bf16_t)u0.x; v[1] = (bf16_t)u0.y; v[2] = (bf16_t)u0.z; v[3] = (bf16_t)u0.w;
  v[4] = (bf16_t)u1.x; v[5] = (bf16_t)u1.y; v[6] = (bf16_t)u1.z; v[7] = (bf16_t)u1.w;
  return v;
}

// ---- transpose 7 128x128 f32 weight blocks into bf16 wt ([n][k] layout) ----
// slots: 0 W1a_t, 1 W1b_t, 2 e_w2t, 3 n_w1a_t, 4 n_w1b_t, 5 n_w2t, 6 c_w1t
__global__ __launch_bounds__(256) void transpose_k(
    const float* __restrict__ e_w1, const float* __restrict__ e_w2,
    const float* __restrict__ n_w1, const float* __restrict__ n_w2,
    const float* __restrict__ c_w1, bf16_t* __restrict__ wt) {
  int b = blockIdx.x;
  const float* src;
  switch (b) {
    case 0: src = e_w1; break;
    case 1: src = e_w1 + 16384; break;
    case 2: src = e_w2; break;
    case 3: src = n_w1; break;
    case 4: src = n_w1 + 16384; break;
    case 5: src = n_w2; break;
    default: src = c_w1; break;
  }
  bf16_t* dst = wt + b * 16384;
  for (int i = threadIdx.x; i < 16384; i += 256) {
    int k = i >> 7, n = i & 127;
    dst[n * 128 + k] = (bf16_t)src[k * 128 + n];
  }
}

// ---- prep: pa = bf16(h@W1a + e_b1), pb = bf16(h@W1b) ----
__global__ __launch_bounds__(256) void prep_k(
    const float* __restrict__ h, const bf16_t* __restrict__ wt,
    const float* __restrict__ e_b1, bf16_t* __restrict__ pa, bf16_t* __restrict__ pb) {
  __shared__ __align__(16) bf16_t Asb[64 * LDST];
  __shared__ __align__(16) bf16_t Bsb[128 * LDST];
  int t = threadIdx.x;
  int node0 = blockIdx.x * 64;
  for (int i = t; i < 1024; i += 256) {
    int rowl = i >> 4, cc = i & 15;
    int node = node0 + rowl; if (node >= NN) node = NN - 1;
    const float4* p = (const float4*)(h + (size_t)node * 128 + cc * 8);
    *(bf16x8*)(Asb + rowl * LDST + cc * 8) = cvt8(p[0], p[1]);
  }
  int lane = t & 63, w = t >> 6;
  int m0 = w * 16, quad = lane >> 4, cix = lane & 15, koff = quad * 8;
  const bf16_t* Arow = Asb + (m0 + cix) * LDST;
  const bf16_t* Bcol = Bsb + cix * LDST;

  bf16_t* outp[2] = {pa, pb};
#pragma unroll
  for (int p = 0; p < 2; ++p) {
    __syncthreads();
    load_B(Bsb, wt + p * 16384, t);
    __syncthreads();
    f32x4 acc[8];
#pragma unroll
    for (int i = 0; i < 8; ++i) acc[i] = (f32x4){0.f, 0.f, 0.f, 0.f};
    gemm_stripe(Arow, Bcol, koff, acc);
#pragma unroll
    for (int nt = 0; nt < 8; ++nt) {
      int colg = nt * 16 + cix;
      float bv = p == 0 ? e_b1[colg] : 0.f;
#pragma unroll
      for (int rix = 0; rix < 4; ++rix) {
        int node = node0 + m0 + quad * 4 + rix;
        if (node < NN) outp[p][(size_t)node * 128 + colg] = (bf16_t)(acc[nt][rix] + bv);
      }
    }
  }
}

// ---- edge kernel: persistent, 16 independent waves, zero loop barriers ----
__global__ __launch_bounds__(1024, 4) void edge_k(
    const bf16_t* __restrict__ pa, const bf16_t* __restrict__ pb,
    const int* __restrict__ ei, const float* __restrict__ eattr,
    const float* __restrict__ x, const bf16_t* __restrict__ wt,
    const float* __restrict__ e_w1, const float* __restrict__ e_b2,
    const float* __restrict__ c_b1, const float* __restrict__ c_w2,
    const float* __restrict__ a_w, const float* __restrict__ a_b,
    float* __restrict__ agg, float* __restrict__ coord_agg, float* __restrict__ cnt) {
  // MFMA-chunk layout: 16B chunk index (nt*256 + kc*16 + cix) holds
  // Bt[n=nt*16+cix][k=kc*8 .. +8]. A wave's fragment read (fixed nt,ks) covers
  // 1KB contiguous -> conflict-free. 32KB per matrix, unpadded.
  __shared__ __align__(16) bf16_t Bs2[16384];       // e_w2, 32768 B
  __shared__ __align__(16) bf16_t Bs6[16384];       // c_w1, 32768 B
  __shared__ __align__(16) bf16_t Ag[NW * 16 * LDST];  // per-wave m stripes, 69632 B

  int t = threadIdx.x;
  for (int cch = t; cch < 2048; cch += 1024) {
    int nt = cch >> 8, rem = cch & 255, kc = rem >> 4, ci = rem & 15;
    int n = nt * 16 + ci;
    *(bf16x8*)(Bs2 + cch * 8) = *(const bf16x8*)(wt + 2 * 16384 + n * 128 + kc * 8);
    *(bf16x8*)(Bs6 + cch * 8) = *(const bf16x8*)(wt + 6 * 16384 + n * 128 + kc * 8);
  }
  __syncthreads();  // the only barrier

  int lane = t & 63, w = t >> 6;
  int quad = lane >> 4, cix = lane & 15, koff = quad * 8;
  bf16_t* Aw = Ag + w * (16 * LDST);  // this wave's private m stripe
  const float* wrp = e_w1 + 256 * 128;
  const float* wep = e_w1 + 257 * 128;
  float a_bv = a_b[0];

  int wg = blockIdx.x * NW + w;
  int nwv = gridDim.x * NW;
  for (int s = wg; s < NE / 16; s += nwv) {
    int eg = s * 16 + cix;  // this lane's edge (duplicated across quads)
    int r = ei[eg], c = ei[NE + eg];
    float d0 = x[r * 3 + 0] - x[c * 3 + 0];
    float d1 = x[r * 3 + 1] - x[c * 3 + 1];
    float d2 = x[r * 3 + 2] - x[c * 3 + 2];
    float rad = d0 * d0 + d1 * d1 + d2 * d2;
    float ea = eattr[eg];
    const bf16_t* par = pa + (size_t)r * 128;
    const bf16_t* pbr = pb + (size_t)c * 128;

    // GEMM1 fused: z1 built in-register as A-fragment, C = z1 @ e_w2
    f32x4 acc[8];
#pragma unroll
    for (int i = 0; i < 8; ++i) acc[i] = (f32x4){0.f, 0.f, 0.f, 0.f};
#pragma unroll
    for (int ks = 0; ks < 4; ++ks) {
      int kk = ks * 32 + koff;
      bf16x8 pa8 = *(const bf16x8*)(par + kk);
      bf16x8 pb8 = *(const bf16x8*)(pbr + kk);
      float4 wr0 = *(const float4*)(wrp + kk);
      float4 wr1 = *(const float4*)(wrp + kk + 4);
      float4 we0 = *(const float4*)(wep + kk);
      float4 we1 = *(const float4*)(wep + kk + 4);
      float wrv[8] = {wr0.x, wr0.y, wr0.z, wr0.w, wr1.x, wr1.y, wr1.z, wr1.w};
      float wev[8] = {we0.x, we0.y, we0.z, we0.w, we1.x, we1.y, we1.z, we1.w};
      bf16x8 af;
#pragma unroll
      for (int j = 0; j < 8; ++j) {
        float z = (float)pa8[j] + (float)pb8[j] + rad * wrv[j] + ea * wev[j];
        af[j] = (bf16_t)siluf(z);
      }
#pragma unroll
      for (int nt = 0; nt < 8; ++nt) {
        bf16x8 b = *(const bf16x8*)(Bs2 + (nt * 256 + (ks * 4 + quad) * 16 + cix) * 8);
        acc[nt] = __builtin_amdgcn_mfma_f32_16x16x32_bf16(af, b, acc[nt], 0, 0, 0);
      }
    }

    // m = silu(. + b2); att = sigmoid(m . a_w + a_b); m *= att; m -> Aw (wave-local)
    float attp[4] = {0.f, 0.f, 0.f, 0.f};
#pragma unroll
    for (int nt = 0; nt < 8; ++nt) {
      int colg = nt * 16 + cix;
      float b2v = e_b2[colg];
      float awv = a_w[colg];
#pragma unroll
      for (int rix = 0; rix < 4; ++rix) {
        float v = siluf(acc[nt][rix] + b2v);
        acc[nt][rix] = v;
        attp[rix] += v * awv;
      }
    }
    float attv[4];
#pragma unroll
    for (int rix = 0; rix < 4; ++rix) {
      float sv = attp[rix];
      sv += __shfl_xor(sv, 1); sv += __shfl_xor(sv, 2);
      sv += __shfl_xor(sv, 4); sv += __shfl_xor(sv, 8);
      attv[rix] = 1.f / (1.f + __expf(-(sv + a_bv)));
    }
#pragma unroll
    for (int nt = 0; nt < 8; ++nt) {
#pragma unroll
      for (int rix = 0; rix < 4; ++rix) {
        float v = acc[nt][rix] * attv[rix];
        Aw[(quad * 4 + rix) * LDST + nt * 16 + cix] = (bf16_t)v;
      }
    }
    // wave-local LDS RAW: in-order per-wave DS + compiler lgkmcnt; no barrier.

    // GEMM2: coord_update = silu(m @ c_w1 + c_b1) . c_w2
    const bf16_t* Arow = Aw + cix * LDST;
#pragma unroll
    for (int i = 0; i < 8; ++i) acc[i] = (f32x4){0.f, 0.f, 0.f, 0.f};
#pragma unroll
    for (int ks = 0; ks < 4; ++ks) {
      bf16x8 a = *(const bf16x8*)(Arow + ks * 32 + koff);
#pragma unroll
      for (int nt = 0; nt < 8; ++nt) {
        bf16x8 b = *(const bf16x8*)(Bs6 + (nt * 256 + (ks * 4 + quad) * 16 + cix) * 8);
        acc[nt] = __builtin_amdgcn_mfma_f32_16x16x32_bf16(a, b, acc[nt], 0, 0, 0);
      }
    }

    float cup[4] = {0.f, 0.f, 0.f, 0.f};
#pragma unroll
    for (int nt = 0; nt < 8; ++nt) {
      int colg = nt * 16 + cix;
      float cb1v = c_b1[colg];
      float cw2v = c_w2[colg];
#pragma unroll
      for (int rix = 0; rix < 4; ++rix) {
        cup[rix] += siluf(acc[nt][rix] + cb1v) * cw2v;
      }
    }

    // coord/cnt atomics: shfl edge data to quad leaders (shfl by ALL lanes)
#pragma unroll
    for (int rix = 0; rix < 4; ++rix) {
      float sv = cup[rix];
      sv += __shfl_xor(sv, 1); sv += __shfl_xor(sv, 2);
      sv += __shfl_xor(sv, 4); sv += __shfl_xor(sv, 8);
      int e = quad * 4 + rix;
      int rr = __shfl(r, e);
      float dd0 = __shfl(d0, e), dd1 = __shfl(d1, e), dd2 = __shfl(d2, e);
      if (cix == 0) {
        atomicAdd(&coord_agg[rr * 3 + 0], dd0 * sv);
        atomicAdd(&coord_agg[rr * 3 + 1], dd1 * sv);
        atomicAdd(&coord_agg[rr * 3 + 2], dd2 * sv);
        atomicAdd(&cnt[rr], 1.0f);
      }
    }

    // scatter gated m into agg: wave-local, uniform row per instr (256B/atomic-op)
#pragma unroll
    for (int fh = 0; fh < 2; ++fh) {
#pragma unroll
      for (int e = 0; e < 16; ++e) {
        int rowb = __shfl(r, e);
        float v = (float)Aw[e * LDST + fh * 64 + lane];
        atomicAdd(&agg[(size_t)rowb * 128 + fh * 64 + lane], v);
      }
    }
  }
}

// ---- node kernel (in-place on d_out) ----
__global__ __launch_bounds__(256) void node_k(
    const float* __restrict__ h, const float* __restrict__ x,
    const bf16_t* __restrict__ wt, const float* __restrict__ n_b1,
    const float* __restrict__ n_b2, const float* __restrict__ cnt,
    float* __restrict__ out) {
  __shared__ __align__(16) bf16_t Asb[64 * LDST];
  __shared__ __align__(16) bf16_t Bsb[128 * LDST];
  int t = threadIdx.x;
  int node0 = blockIdx.x * 64;
  const float* agg = out;                // accumulated by edge_k
  float* xout = out + (size_t)NN * 128;  // holds coord_agg on entry

  if (t < 192) {
    int node = node0 + t / 3;
    int d = t - (t / 3) * 3;
    if (node < NN) {
      float c = cnt[node];
      float denom = c > 1.f ? c : 1.f;
      float xo = x[node * 3 + d] + xout[node * 3 + d] / denom;
      xout[node * 3 + d] = xo;
    }
  }

  for (int i = t; i < 1024; i += 256) {
    int rowl = i >> 4, cc = i & 15;
    int node = node0 + rowl; if (node >= NN) node = NN - 1;
    const float4* p = (const float4*)(h + (size_t)node * 128 + cc * 8);
    *(bf16x8*)(Asb + rowl * LDST + cc * 8) = cvt8(p[0], p[1]);
  }
  load_B(Bsb, wt + 3 * 16384, t);  // n_w1a_t
  __syncthreads();

  int lane = t & 63, w = t >> 6;
  int m0 = w * 16, quad = lane >> 4, cix = lane & 15, koff = quad * 8;
  const bf16_t* Arow = Asb + (m0 + cix) * LDST;
  const bf16_t* Bcol = Bsb + cix * LDST;

  f32x4 acc[8];
#pragma unroll
  for (int i = 0; i < 8; ++i) acc[i] = (f32x4){0.f, 0.f, 0.f, 0.f};
  gemm_stripe(Arow, Bcol, koff, acc);  // h @ n_w1a

  __syncthreads();

  for (int i = t; i < 1024; i += 256) {
    int rowl = i >> 4, cc = i & 15;
    int node = node0 + rowl; if (node >= NN) node = NN - 1;
    const float4* p = (const float4*)(agg + (size_t)node * 128 + cc * 8);
    *(bf16x8*)(Asb + rowl * LDST + cc * 8) = cvt8(p[0], p[1]);
  }
  load_B(Bsb, wt + 4 * 16384, t);  // n_w1b_t
  __syncthreads();
  gemm_stripe(Arow, Bcol, koff, acc);  // += agg @ n_w1b

#pragma unroll
  for (int nt = 0; nt < 8; ++nt) {
    int colg = nt * 16 + cix;
    float b1v = n_b1[colg];
#pragma unroll
    for (int rix = 0; rix < 4; ++rix) {
      float u = siluf(acc[nt][rix] + b1v);
      Asb[(m0 + quad * 4 + rix) * LDST + colg] = (bf16_t)u;
    }
  }
  __syncthreads();
  load_B(Bsb, wt + 5 * 16384, t);  // n_w2t
  __syncthreads();

#pragma unroll
  for (int i = 0; i < 8; ++i) acc[i] = (f32x4){0.f, 0.f, 0.f, 0.f};
  gemm_stripe(Arow, Bcol, koff, acc);  // u @ n_w2

#pragma unroll
  for (int nt = 0; nt < 8; ++nt) {
    int colg = nt * 16 + cix;
    float b2v = n_b2[colg];
#pragma unroll
    for (int rix = 0; rix < 4; ++rix) {
      int node = node0 + m0 + quad * 4 + rix;
      if (node < NN) {
        float ho = h[(size_t)node * 128 + colg] + acc[nt][rix] + b2v;
        out[(size_t)node * 128 + colg] = ho;
      }
    }
  }
}

extern "C" void kernel_launch(void* const* d_in, const int* in_sizes, int n_in,
                              void* d_out, int out_size, void* d_ws, size_t ws_size,
                              hipStream_t stream) {
  const float* h = (const float*)d_in[0];
  const float* x = (const float*)d_in[1];
  const int* ei = (const int*)d_in[2];
  const float* eattr = (const float*)d_in[3];
  const float* e_w1 = (const float*)d_in[4];
  const float* e_b1 = (const float*)d_in[5];
  const float* e_w2 = (const float*)d_in[6];
  const float* e_b2 = (const float*)d_in[7];
  const float* n_w1 = (const float*)d_in[8];
  const float* n_b1 = (const float*)d_in[9];
  const float* n_w2 = (const float*)d_in[10];
  const float* n_b2 = (const float*)d_in[11];
  const float* c_w1 = (const float*)d_in[12];
  const float* c_b1 = (const float*)d_in[13];
  const float* c_w2 = (const float*)d_in[14];
  const float* a_w = (const float*)d_in[15];
  const float* a_b = (const float*)d_in[16];

  float* outp = (float*)d_out;
  float* agg = outp;                           // N*128 f32 (h_out region)
  float* coord_agg = outp + (size_t)NN * 128;  // N*3 f32 (x_out region)

  // ws layout: pa 12.8MB | pb 12.8MB | cnt 200KB | wt 229KB = 26.03 MB total
  char* ws = (char*)d_ws;
  bf16_t* pa = (bf16_t*)(ws + 0);
  bf16_t* pb = (bf16_t*)(ws + 12800000);
  float* cnt = (float*)(ws + 25600000);
  bf16_t* wt = (bf16_t*)(ws + 25800000);

  hipMemsetAsync(d_out, 0, (size_t)(NN * 131) * 4, stream);
  hipMemsetAsync(ws + 25600000, 0, 200000, stream);
  transpose_k<<<7, 256, 0, stream>>>(e_w1, e_w2, n_w1, n_w2, c_w1, wt);
  prep_k<<<(NN + 63) / 64, 256, 0, stream>>>(h, wt, e_b1, pa, pb);
  edge_k<<<256, 1024, 0, stream>>>(pa, pb, ei, eattr, x, wt, e_w1, e_b2, c_b1,
                                   c_w2, a_w, a_b, agg, coord_agg, cnt);
  node_k<<<(NN + 63) / 64, 256, 0, stream>>>(h, x, wt, n_b1, n_b2, cnt, outp);
}

// Round 7
// 734.674 us; speedup vs baseline: 1.1547x; 1.0296x over previous
//
#include <hip/hip_runtime.h>

// EGNN layer (round 7): round-6 zero-barrier edge kernel + SOFTWARE PIPELINE.
//  - Round-6 post-mortem: latency-bound (VALU 33%, MFMA 3.8%, no pipe saturated).
//    Serial chain per iter: ei -> random pa/pb gather -> GEMM1 -> GEMM2 -> atomics.
//  - Fix: prefetch next stripe's ei at loop top (hidden by GEMM1); prefetch next
//    pa/pb fragments + x/eattr right after GEMM1 consumes current ones (hidden by
//    epilogue+GEMM2+atomics); rotate registers at loop bottom. VGPR ~110 < 128 cap.
//  - Weights LDS-resident in MFMA-chunk layout (conflict-free); per-wave private
//    m stripe; one barrier total; f32 atomics into d_out.

#define NN 50000
#define NE 800000
#define LDST 136
#define NW 16  // waves per edge_k block

typedef __bf16 bf16_t;
typedef __bf16 bf16x8 __attribute__((ext_vector_type(8)));
typedef float f32x4 __attribute__((ext_vector_type(4)));

__device__ __forceinline__ float siluf(float v) { return v / (1.f + __expf(-v)); }

__device__ __forceinline__ void gemm_stripe(const bf16_t* Arow, const bf16_t* Bcol,
                                            int koff, f32x4 acc[8]) {
#pragma unroll
  for (int ks = 0; ks < 4; ++ks) {
    bf16x8 a = *(const bf16x8*)(Arow + ks * 32 + koff);
#pragma unroll
    for (int nt = 0; nt < 8; ++nt) {
      bf16x8 b = *(const bf16x8*)(Bcol + nt * 16 * LDST + ks * 32 + koff);
      acc[nt] = __builtin_amdgcn_mfma_f32_16x16x32_bf16(a, b, acc[nt], 0, 0, 0);
    }
  }
}

__device__ __forceinline__ void load_B(bf16_t* Bsb, const bf16_t* __restrict__ src, int t) {
  for (int i = t; i < 2048; i += 256) {
    int n = i >> 4, cc = i & 15;
    *(bf16x8*)(Bsb + n * LDST + cc * 8) = *(const bf16x8*)(src + n * 128 + cc * 8);
  }
}

__device__ __forceinline__ bf16x8 cvt8(float4 u0, float4 u1) {
  bf16x8 v;
  v[0] = (bf16_t)u0.x; v[1] = (bf16_t)u0.y; v[2] = (bf16_t)u0.z; v[3] = (bf16_t)u0.w;
  v[4] = (bf16_t)u1.x; v[5] = (bf16_t)u1.y; v[6] = (bf16_t)u1.z; v[7] = (bf16_t)u1.w;
  return v;
}

// ---- transpose 7 128x128 f32 weight blocks into bf16 wt ([n][k] layout) ----
// slots: 0 W1a_t, 1 W1b_t, 2 e_w2t, 3 n_w1a_t, 4 n_w1b_t, 5 n_w2t, 6 c_w1t
__global__ __launch_bounds__(256) void transpose_k(
    const float* __restrict__ e_w1, const float* __restrict__ e_w2,
    const float* __restrict__ n_w1, const float* __restrict__ n_w2,
    const float* __restrict__ c_w1, bf16_t* __restrict__ wt) {
  int b = blockIdx.x;
  const float* src;
  switch (b) {
    case 0: src = e_w1; break;
    case 1: src = e_w1 + 16384; break;
    case 2: src = e_w2; break;
    case 3: src = n_w1; break;
    case 4: src = n_w1 + 16384; break;
    case 5: src = n_w2; break;
    default: src = c_w1; break;
  }
  bf16_t* dst = wt + b * 16384;
  for (int i = threadIdx.x; i < 16384; i += 256) {
    int k = i >> 7, n = i & 127;
    dst[n * 128 + k] = (bf16_t)src[k * 128 + n];
  }
}

// ---- prep: pa = bf16(h@W1a + e_b1), pb = bf16(h@W1b) ----
__global__ __launch_bounds__(256) void prep_k(
    const float* __restrict__ h, const bf16_t* __restrict__ wt,
    const float* __restrict__ e_b1, bf16_t* __restrict__ pa, bf16_t* __restrict__ pb) {
  __shared__ __align__(16) bf16_t Asb[64 * LDST];
  __shared__ __align__(16) bf16_t Bsb[128 * LDST];
  int t = threadIdx.x;
  int node0 = blockIdx.x * 64;
  for (int i = t; i < 1024; i += 256) {
    int rowl = i >> 4, cc = i & 15;
    int node = node0 + rowl; if (node >= NN) node = NN - 1;
    const float4* p = (const float4*)(h + (size_t)node * 128 + cc * 8);
    *(bf16x8*)(Asb + rowl * LDST + cc * 8) = cvt8(p[0], p[1]);
  }
  int lane = t & 63, w = t >> 6;
  int m0 = w * 16, quad = lane >> 4, cix = lane & 15, koff = quad * 8;
  const bf16_t* Arow = Asb + (m0 + cix) * LDST;
  const bf16_t* Bcol = Bsb + cix * LDST;

  bf16_t* outp[2] = {pa, pb};
#pragma unroll
  for (int p = 0; p < 2; ++p) {
    __syncthreads();
    load_B(Bsb, wt + p * 16384, t);
    __syncthreads();
    f32x4 acc[8];
#pragma unroll
    for (int i = 0; i < 8; ++i) acc[i] = (f32x4){0.f, 0.f, 0.f, 0.f};
    gemm_stripe(Arow, Bcol, koff, acc);
#pragma unroll
    for (int nt = 0; nt < 8; ++nt) {
      int colg = nt * 16 + cix;
      float bv = p == 0 ? e_b1[colg] : 0.f;
#pragma unroll
      for (int rix = 0; rix < 4; ++rix) {
        int node = node0 + m0 + quad * 4 + rix;
        if (node < NN) outp[p][(size_t)node * 128 + colg] = (bf16_t)(acc[nt][rix] + bv);
      }
    }
  }
}

// ---- edge kernel: persistent, zero loop barriers, software-pipelined ----
__global__ __launch_bounds__(1024, 4) void edge_k(
    const bf16_t* __restrict__ pa, const bf16_t* __restrict__ pb,
    const int* __restrict__ ei, const float* __restrict__ eattr,
    const float* __restrict__ x, const bf16_t* __restrict__ wt,
    const float* __restrict__ e_w1, const float* __restrict__ e_b2,
    const float* __restrict__ c_b1, const float* __restrict__ c_w2,
    const float* __restrict__ a_w, const float* __restrict__ a_b,
    float* __restrict__ agg, float* __restrict__ coord_agg, float* __restrict__ cnt) {
  // MFMA-chunk layout: chunk (nt*256 + kc*16 + cix) holds Bt[n=nt*16+cix][k=kc*8..+8];
  // a wave's fragment read covers 1KB contiguous -> conflict-free.
  __shared__ __align__(16) bf16_t Bs2[16384];          // e_w2,  32768 B
  __shared__ __align__(16) bf16_t Bs6[16384];          // c_w1,  32768 B
  __shared__ __align__(16) bf16_t Ag[NW * 16 * LDST];  // per-wave m stripes

  int t = threadIdx.x;
  for (int cch = t; cch < 2048; cch += 1024) {
    int nt = cch >> 8, rem = cch & 255, kc = rem >> 4, ci = rem & 15;
    int n = nt * 16 + ci;
    *(bf16x8*)(Bs2 + cch * 8) = *(const bf16x8*)(wt + 2 * 16384 + n * 128 + kc * 8);
    *(bf16x8*)(Bs6 + cch * 8) = *(const bf16x8*)(wt + 6 * 16384 + n * 128 + kc * 8);
  }
  __syncthreads();  // the only barrier

  int lane = t & 63, w = t >> 6;
  int quad = lane >> 4, cix = lane & 15, koff = quad * 8;
  bf16_t* Aw = Ag + w * (16 * LDST);
  const float* wrp = e_w1 + 256 * 128;
  const float* wep = e_w1 + 257 * 128;
  float a_bv = a_b[0];

  int wg = blockIdx.x * NW + w;
  int nwv = gridDim.x * NW;
  int nstripe = NE / 16;

  // ---- pipeline prologue: fully load stage for s = wg ----
  int eg = wg * 16 + cix;
  int r = ei[eg], c = ei[NE + eg];
  float ea = eattr[eg];
  float d0 = x[r * 3 + 0] - x[c * 3 + 0];
  float d1 = x[r * 3 + 1] - x[c * 3 + 1];
  float d2 = x[r * 3 + 2] - x[c * 3 + 2];
  float rad = d0 * d0 + d1 * d1 + d2 * d2;
  bf16x8 paf[4], pbf[4];
#pragma unroll
  for (int ks = 0; ks < 4; ++ks) {
    paf[ks] = *(const bf16x8*)(pa + (size_t)r * 128 + ks * 32 + koff);
    pbf[ks] = *(const bf16x8*)(pb + (size_t)c * 128 + ks * 32 + koff);
  }

  for (int s = wg; s < nstripe; s += nwv) {
    // (1) issue next stripe's index loads (hidden by GEMM1)
    int sn = s + nwv;
    int sl = sn < nstripe ? sn : s;
    int egn = sl * 16 + cix;
    int rn = ei[egn], cn = ei[NE + egn];

    // (2) GEMM1 fused: z1 from in-register paf/pbf, C = z1 @ e_w2
    f32x4 acc[8];
#pragma unroll
    for (int i = 0; i < 8; ++i) acc[i] = (f32x4){0.f, 0.f, 0.f, 0.f};
#pragma unroll
    for (int ks = 0; ks < 4; ++ks) {
      int kk = ks * 32 + koff;
      float4 wr0 = *(const float4*)(wrp + kk);
      float4 wr1 = *(const float4*)(wrp + kk + 4);
      float4 we0 = *(const float4*)(wep + kk);
      float4 we1 = *(const float4*)(wep + kk + 4);
      float wrv[8] = {wr0.x, wr0.y, wr0.z, wr0.w, wr1.x, wr1.y, wr1.z, wr1.w};
      float wev[8] = {we0.x, we0.y, we0.z, we0.w, we1.x, we1.y, we1.z, we1.w};
      bf16x8 af;
#pragma unroll
      for (int j = 0; j < 8; ++j) {
        float z = (float)paf[ks][j] + (float)pbf[ks][j] + rad * wrv[j] + ea * wev[j];
        af[j] = (bf16_t)siluf(z);
      }
#pragma unroll
      for (int nt = 0; nt < 8; ++nt) {
        bf16x8 b = *(const bf16x8*)(Bs2 + (nt * 256 + (ks * 4 + quad) * 16 + cix) * 8);
        acc[nt] = __builtin_amdgcn_mfma_f32_16x16x32_bf16(af, b, acc[nt], 0, 0, 0);
      }
    }

    // (3) current fragments consumed -> issue next gathers + geometry loads
    //     (latency hidden by epilogue + GEMM2 + atomics below)
    bf16x8 pafn[4], pbfn[4];
#pragma unroll
    for (int ks = 0; ks < 4; ++ks) {
      pafn[ks] = *(const bf16x8*)(pa + (size_t)rn * 128 + ks * 32 + koff);
      pbfn[ks] = *(const bf16x8*)(pb + (size_t)cn * 128 + ks * 32 + koff);
    }
    float ean = eattr[egn];
    float xr0 = x[rn * 3 + 0], xr1 = x[rn * 3 + 1], xr2 = x[rn * 3 + 2];
    float xc0 = x[cn * 3 + 0], xc1 = x[cn * 3 + 1], xc2 = x[cn * 3 + 2];

    // (4) epilogue 1: m = silu(.+b2); att gate; m -> Aw (wave-local)
    float attp[4] = {0.f, 0.f, 0.f, 0.f};
#pragma unroll
    for (int nt = 0; nt < 8; ++nt) {
      int colg = nt * 16 + cix;
      float b2v = e_b2[colg];
      float awv = a_w[colg];
#pragma unroll
      for (int rix = 0; rix < 4; ++rix) {
        float v = siluf(acc[nt][rix] + b2v);
        acc[nt][rix] = v;
        attp[rix] += v * awv;
      }
    }
    float attv[4];
#pragma unroll
    for (int rix = 0; rix < 4; ++rix) {
      float sv = attp[rix];
      sv += __shfl_xor(sv, 1); sv += __shfl_xor(sv, 2);
      sv += __shfl_xor(sv, 4); sv += __shfl_xor(sv, 8);
      attv[rix] = 1.f / (1.f + __expf(-(sv + a_bv)));
    }
#pragma unroll
    for (int nt = 0; nt < 8; ++nt) {
#pragma unroll
      for (int rix = 0; rix < 4; ++rix) {
        float v = acc[nt][rix] * attv[rix];
        Aw[(quad * 4 + rix) * LDST + nt * 16 + cix] = (bf16_t)v;
      }
    }

    // GEMM2: coord_update = silu(m @ c_w1 + c_b1) . c_w2   (wave-local LDS RAW)
    const bf16_t* Arow = Aw + cix * LDST;
#pragma unroll
    for (int i = 0; i < 8; ++i) acc[i] = (f32x4){0.f, 0.f, 0.f, 0.f};
#pragma unroll
    for (int ks = 0; ks < 4; ++ks) {
      bf16x8 a = *(const bf16x8*)(Arow + ks * 32 + koff);
#pragma unroll
      for (int nt = 0; nt < 8; ++nt) {
        bf16x8 b = *(const bf16x8*)(Bs6 + (nt * 256 + (ks * 4 + quad) * 16 + cix) * 8);
        acc[nt] = __builtin_amdgcn_mfma_f32_16x16x32_bf16(a, b, acc[nt], 0, 0, 0);
      }
    }

    float cup[4] = {0.f, 0.f, 0.f, 0.f};
#pragma unroll
    for (int nt = 0; nt < 8; ++nt) {
      int colg = nt * 16 + cix;
      float cb1v = c_b1[colg];
      float cw2v = c_w2[colg];
#pragma unroll
      for (int rix = 0; rix < 4; ++rix) {
        cup[rix] += siluf(acc[nt][rix] + cb1v) * cw2v;
      }
    }

    // (5) coord/cnt atomics
#pragma unroll
    for (int rix = 0; rix < 4; ++rix) {
      float sv = cup[rix];
      sv += __shfl_xor(sv, 1); sv += __shfl_xor(sv, 2);
      sv += __shfl_xor(sv, 4); sv += __shfl_xor(sv, 8);
      int e = quad * 4 + rix;
      int rr = __shfl(r, e);
      float dd0 = __shfl(d0, e), dd1 = __shfl(d1, e), dd2 = __shfl(d2, e);
      if (cix == 0) {
        atomicAdd(&coord_agg[rr * 3 + 0], dd0 * sv);
        atomicAdd(&coord_agg[rr * 3 + 1], dd1 * sv);
        atomicAdd(&coord_agg[rr * 3 + 2], dd2 * sv);
        atomicAdd(&cnt[rr], 1.0f);
      }
    }

    // scatter gated m into agg (wave-local, uniform row per instruction)
#pragma unroll
    for (int fh = 0; fh < 2; ++fh) {
#pragma unroll
      for (int e = 0; e < 16; ++e) {
        int rowb = __shfl(r, e);
        float v = (float)Aw[e * LDST + fh * 64 + lane];
        atomicAdd(&agg[(size_t)rowb * 128 + fh * 64 + lane], v);
      }
    }

    // (6) rotate pipeline registers (waits on step-3 loads happen here)
    r = rn; c = cn; eg = egn; ea = ean;
    d0 = xr0 - xc0; d1 = xr1 - xc1; d2 = xr2 - xc2;
    rad = d0 * d0 + d1 * d1 + d2 * d2;
#pragma unroll
    for (int ks = 0; ks < 4; ++ks) { paf[ks] = pafn[ks]; pbf[ks] = pbfn[ks]; }
  }
}

// ---- node kernel (in-place on d_out) ----
__global__ __launch_bounds__(256) void node_k(
    const float* __restrict__ h, const float* __restrict__ x,
    const bf16_t* __restrict__ wt, const float* __restrict__ n_b1,
    const float* __restrict__ n_b2, const float* __restrict__ cnt,
    float* __restrict__ out) {
  __shared__ __align__(16) bf16_t Asb[64 * LDST];
  __shared__ __align__(16) bf16_t Bsb[128 * LDST];
  int t = threadIdx.x;
  int node0 = blockIdx.x * 64;
  const float* agg = out;
  float* xout = out + (size_t)NN * 128;

  if (t < 192) {
    int node = node0 + t / 3;
    int d = t - (t / 3) * 3;
    if (node < NN) {
      float c = cnt[node];
      float denom = c > 1.f ? c : 1.f;
      float xo = x[node * 3 + d] + xout[node * 3 + d] / denom;
      xout[node * 3 + d] = xo;
    }
  }

  for (int i = t; i < 1024; i += 256) {
    int rowl = i >> 4, cc = i & 15;
    int node = node0 + rowl; if (node >= NN) node = NN - 1;
    const float4* p = (const float4*)(h + (size_t)node * 128 + cc * 8);
    *(bf16x8*)(Asb + rowl * LDST + cc * 8) = cvt8(p[0], p[1]);
  }
  load_B(Bsb, wt + 3 * 16384, t);  // n_w1a_t
  __syncthreads();

  int lane = t & 63, w = t >> 6;
  int m0 = w * 16, quad = lane >> 4, cix = lane & 15, koff = quad * 8;
  const bf16_t* Arow = Asb + (m0 + cix) * LDST;
  const bf16_t* Bcol = Bsb + cix * LDST;

  f32x4 acc[8];
#pragma unroll
  for (int i = 0; i < 8; ++i) acc[i] = (f32x4){0.f, 0.f, 0.f, 0.f};
  gemm_stripe(Arow, Bcol, koff, acc);  // h @ n_w1a

  __syncthreads();

  for (int i = t; i < 1024; i += 256) {
    int rowl = i >> 4, cc = i & 15;
    int node = node0 + rowl; if (node >= NN) node = NN - 1;
    const float4* p = (const float4*)(agg + (size_t)node * 128 + cc * 8);
    *(bf16x8*)(Asb + rowl * LDST + cc * 8) = cvt8(p[0], p[1]);
  }
  load_B(Bsb, wt + 4 * 16384, t);  // n_w1b_t
  __syncthreads();
  gemm_stripe(Arow, Bcol, koff, acc);  // += agg @ n_w1b

#pragma unroll
  for (int nt = 0; nt < 8; ++nt) {
    int colg = nt * 16 + cix;
    float b1v = n_b1[colg];
#pragma unroll
    for (int rix = 0; rix < 4; ++rix) {
      float u = siluf(acc[nt][rix] + b1v);
      Asb[(m0 + quad * 4 + rix) * LDST + colg] = (bf16_t)u;
    }
  }
  __syncthreads();
  load_B(Bsb, wt + 5 * 16384, t);  // n_w2t
  __syncthreads();

#pragma unroll
  for (int i = 0; i < 8; ++i) acc[i] = (f32x4){0.f, 0.f, 0.f, 0.f};
  gemm_stripe(Arow, Bcol, koff, acc);  // u @ n_w2

#pragma unroll
  for (int nt = 0; nt < 8; ++nt) {
    int colg = nt * 16 + cix;
    float b2v = n_b2[colg];
#pragma unroll
    for (int rix = 0; rix < 4; ++rix) {
      int node = node0 + m0 + quad * 4 + rix;
      if (node < NN) {
        float ho = h[(size_t)node * 128 + colg] + acc[nt][rix] + b2v;
        out[(size_t)node * 128 + colg] = ho;
      }
    }
  }
}

extern "C" void kernel_launch(void* const* d_in, const int* in_sizes, int n_in,
                              void* d_out, int out_size, void* d_ws, size_t ws_size,
                              hipStream_t stream) {
  const float* h = (const float*)d_in[0];
  const float* x = (const float*)d_in[1];
  const int* ei = (const int*)d_in[2];
  const float* eattr = (const float*)d_in[3];
  const float* e_w1 = (const float*)d_in[4];
  const float* e_b1 = (const float*)d_in[5];
  const float* e_w2 = (const float*)d_in[6];
  const float* e_b2 = (const float*)d_in[7];
  const float* n_w1 = (const float*)d_in[8];
  const float* n_b1 = (const float*)d_in[9];
  const float* n_w2 = (const float*)d_in[10];
  const float* n_b2 = (const float*)d_in[11];
  const float* c_w1 = (const float*)d_in[12];
  const float* c_b1 = (const float*)d_in[13];
  const float* c_w2 = (const float*)d_in[14];
  const float* a_w = (const float*)d_in[15];
  const float* a_b = (const float*)d_in[16];

  float* outp = (float*)d_out;
  float* agg = outp;                           // N*128 f32 (h_out region)
  float* coord_agg = outp + (size_t)NN * 128;  // N*3 f32 (x_out region)

  // ws layout: pa 12.8MB | pb 12.8MB | cnt 200KB | wt 229KB = 26.03 MB total
  char* ws = (char*)d_ws;
  bf16_t* pa = (bf16_t*)(ws + 0);
  bf16_t* pb = (bf16_t*)(ws + 12800000);
  float* cnt = (float*)(ws + 25600000);
  bf16_t* wt = (bf16_t*)(ws + 25800000);

  hipMemsetAsync(d_out, 0, (size_t)(NN * 131) * 4, stream);
  hipMemsetAsync(ws + 25600000, 0, 200000, stream);
  transpose_k<<<7, 256, 0, stream>>>(e_w1, e_w2, n_w1, n_w2, c_w1, wt);
  prep_k<<<(NN + 63) / 64, 256, 0, stream>>>(h, wt, e_b1, pa, pb);
  edge_k<<<256, 1024, 0, stream>>>(pa, pb, ei, eattr, x, wt, e_w1, e_b2, c_b1,
                                   c_w2, a_w, a_b, agg, coord_agg, cnt);
  node_k<<<(NN + 63) / 64, 256, 0, stream>>>(h, x, wt, n_b1, n_b2, cnt, outp);
}

// Round 8
// 606.834 us; speedup vs baseline: 1.3980x; 1.2107x over previous
//
#include <hip/hip_runtime.h>

// EGNN layer (round 8): COUNTING-SORT edges by row + merged atomic scatter.
//  - Round-7 post-mortem: FETCH 670MB / WRITE 570MB >> algorithmic need; the
//    102M random 4B atomic RMWs into 25.6MB agg thrash L2 -> HBM RMW traffic.
//  - Fix: counting sort by row (hist -> 2-level scan -> place). edge_k walks
//    perm in CONTIGUOUS 13-stripe spans per wave => each wave owns ~13 rows
//    (private, L2-local); within a stripe, segmented wave-uniform run detection
//    merges the scatter: ~2 runs/stripe => ~8x fewer atomic dwords.
//  - cnt comes free from the histogram (deg), coord atomics merged per run.
//  - Weights LDS-resident (MFMA-chunk layout, conflict-free), per-wave private
//    m stripe, one barrier total (round-6 structure).

#define NN 50000
#define NE 800000
#define LDST 136
#define NW 16        // waves per edge_k block
#define NSTRIPE (NE / 16)
#define EGRID 256
#define SPAN ((NSTRIPE + EGRID * NW - 1) / (EGRID * NW))  // 13

typedef __bf16 bf16_t;
typedef __bf16 bf16x8 __attribute__((ext_vector_type(8)));
typedef float f32x4 __attribute__((ext_vector_type(4)));

__device__ __forceinline__ float siluf(float v) { return v / (1.f + __expf(-v)); }

__device__ __forceinline__ void gemm_stripe(const bf16_t* Arow, const bf16_t* Bcol,
                                            int koff, f32x4 acc[8]) {
#pragma unroll
  for (int ks = 0; ks < 4; ++ks) {
    bf16x8 a = *(const bf16x8*)(Arow + ks * 32 + koff);
#pragma unroll
    for (int nt = 0; nt < 8; ++nt) {
      bf16x8 b = *(const bf16x8*)(Bcol + nt * 16 * LDST + ks * 32 + koff);
      acc[nt] = __builtin_amdgcn_mfma_f32_16x16x32_bf16(a, b, acc[nt], 0, 0, 0);
    }
  }
}

__device__ __forceinline__ void load_B(bf16_t* Bsb, const bf16_t* __restrict__ src, int t) {
  for (int i = t; i < 2048; i += 256) {
    int n = i >> 4, cc = i & 15;
    *(bf16x8*)(Bsb + n * LDST + cc * 8) = *(const bf16x8*)(src + n * 128 + cc * 8);
  }
}

__device__ __forceinline__ bf16x8 cvt8(float4 u0, float4 u1) {
  bf16x8 v;
  v[0] = (bf16_t)u0.x; v[1] = (bf16_t)u0.y; v[2] = (bf16_t)u0.z; v[3] = (bf16_t)u0.w;
  v[4] = (bf16_t)u1.x; v[5] = (bf16_t)u1.y; v[6] = (bf16_t)u1.z; v[7] = (bf16_t)u1.w;
  return v;
}

// ---- transpose 7 128x128 f32 weight blocks into bf16 wt ([n][k] layout) ----
// slots: 0 W1a_t, 1 W1b_t, 2 e_w2t, 3 n_w1a_t, 4 n_w1b_t, 5 n_w2t, 6 c_w1t
__global__ __launch_bounds__(256) void transpose_k(
    const float* __restrict__ e_w1, const float* __restrict__ e_w2,
    const float* __restrict__ n_w1, const float* __restrict__ n_w2,
    const float* __restrict__ c_w1, bf16_t* __restrict__ wt) {
  int b = blockIdx.x;
  const float* src;
  switch (b) {
    case 0: src = e_w1; break;
    case 1: src = e_w1 + 16384; break;
    case 2: src = e_w2; break;
    case 3: src = n_w1; break;
    case 4: src = n_w1 + 16384; break;
    case 5: src = n_w2; break;
    default: src = c_w1; break;
  }
  bf16_t* dst = wt + b * 16384;
  for (int i = threadIdx.x; i < 16384; i += 256) {
    int k = i >> 7, n = i & 127;
    dst[n * 128 + k] = (bf16_t)src[k * 128 + n];
  }
}

// ---- prep: pa = bf16(h@W1a + e_b1), pb = bf16(h@W1b) ----
__global__ __launch_bounds__(256) void prep_k(
    const float* __restrict__ h, const bf16_t* __restrict__ wt,
    const float* __restrict__ e_b1, bf16_t* __restrict__ pa, bf16_t* __restrict__ pb) {
  __shared__ __align__(16) bf16_t Asb[64 * LDST];
  __shared__ __align__(16) bf16_t Bsb[128 * LDST];
  int t = threadIdx.x;
  int node0 = blockIdx.x * 64;
  for (int i = t; i < 1024; i += 256) {
    int rowl = i >> 4, cc = i & 15;
    int node = node0 + rowl; if (node >= NN) node = NN - 1;
    const float4* p = (const float4*)(h + (size_t)node * 128 + cc * 8);
    *(bf16x8*)(Asb + rowl * LDST + cc * 8) = cvt8(p[0], p[1]);
  }
  int lane = t & 63, w = t >> 6;
  int m0 = w * 16, quad = lane >> 4, cix = lane & 15, koff = quad * 8;
  const bf16_t* Arow = Asb + (m0 + cix) * LDST;
  const bf16_t* Bcol = Bsb + cix * LDST;

  bf16_t* outp[2] = {pa, pb};
#pragma unroll
  for (int p = 0; p < 2; ++p) {
    __syncthreads();
    load_B(Bsb, wt + p * 16384, t);
    __syncthreads();
    f32x4 acc[8];
#pragma unroll
    for (int i = 0; i < 8; ++i) acc[i] = (f32x4){0.f, 0.f, 0.f, 0.f};
    gemm_stripe(Arow, Bcol, koff, acc);
#pragma unroll
    for (int nt = 0; nt < 8; ++nt) {
      int colg = nt * 16 + cix;
      float bv = p == 0 ? e_b1[colg] : 0.f;
#pragma unroll
      for (int rix = 0; rix < 4; ++rix) {
        int node = node0 + m0 + quad * 4 + rix;
        if (node < NN) outp[p][(size_t)node * 128 + colg] = (bf16_t)(acc[nt][rix] + bv);
      }
    }
  }
}

// ---- counting sort by row: hist -> scan (2-level) -> place ----
__global__ __launch_bounds__(256) void hist_k(const int* __restrict__ ei,
                                              int* __restrict__ deg) {
  int e = blockIdx.x * 256 + threadIdx.x;
  if (e < NE) atomicAdd(&deg[ei[e]], 1);
}

__global__ __launch_bounds__(1024) void scan1_k(const int* __restrict__ deg,
                                                int* __restrict__ curs,
                                                int* __restrict__ bsum) {
  __shared__ int sm[1024];
  int t = threadIdx.x;
  int i = blockIdx.x * 1024 + t;
  int v = (i < NN) ? deg[i] : 0;
  sm[t] = v;
  __syncthreads();
  for (int off = 1; off < 1024; off <<= 1) {
    int add = (t >= off) ? sm[t - off] : 0;
    __syncthreads();
    sm[t] += add;
    __syncthreads();
  }
  if (i < NN) curs[i] = sm[t] - v;  // exclusive within block
  if (t == 1023) bsum[blockIdx.x] = sm[1023];
}

__global__ void scan2_k(int* __restrict__ bsum, int nb) {
  if (threadIdx.x == 0) {
    int acc = 0;
    for (int b = 0; b < nb; ++b) { int v = bsum[b]; bsum[b] = acc; acc += v; }
  }
}

__global__ __launch_bounds__(1024) void scan3_k(int* __restrict__ curs,
                                                const int* __restrict__ bsum) {
  int i = blockIdx.x * 1024 + threadIdx.x;
  if (i < NN) curs[i] += bsum[blockIdx.x];
}

__global__ __launch_bounds__(256) void place_k(const int* __restrict__ ei,
                                               int* __restrict__ curs,
                                               int* __restrict__ perm) {
  int e = blockIdx.x * 256 + threadIdx.x;
  if (e < NE) {
    int row = ei[e];
    int pos = atomicAdd(&curs[row], 1);
    perm[pos] = e;
  }
}

// ---- edge kernel: persistent, sorted edges, contiguous spans, merged scatter ----
__global__ __launch_bounds__(1024, 4) void edge_k(
    const bf16_t* __restrict__ pa, const bf16_t* __restrict__ pb,
    const int* __restrict__ ei, const int* __restrict__ perm,
    const float* __restrict__ eattr, const float* __restrict__ x,
    const bf16_t* __restrict__ wt, const float* __restrict__ e_w1,
    const float* __restrict__ e_b2, const float* __restrict__ c_b1,
    const float* __restrict__ c_w2, const float* __restrict__ a_w,
    const float* __restrict__ a_b, float* __restrict__ agg,
    float* __restrict__ coord_agg) {
  __shared__ __align__(16) bf16_t Bs2[16384];          // e_w2 (MFMA-chunk layout)
  __shared__ __align__(16) bf16_t Bs6[16384];          // c_w1
  __shared__ __align__(16) bf16_t Ag[NW * 16 * LDST];  // per-wave m stripes

  int t = threadIdx.x;
  for (int cch = t; cch < 2048; cch += 1024) {
    int nt = cch >> 8, rem = cch & 255, kc = rem >> 4, ci = rem & 15;
    int n = nt * 16 + ci;
    *(bf16x8*)(Bs2 + cch * 8) = *(const bf16x8*)(wt + 2 * 16384 + n * 128 + kc * 8);
    *(bf16x8*)(Bs6 + cch * 8) = *(const bf16x8*)(wt + 6 * 16384 + n * 128 + kc * 8);
  }
  __syncthreads();  // the only barrier

  int lane = t & 63, w = t >> 6;
  int quad = lane >> 4, cix = lane & 15, koff = quad * 8;
  bf16_t* Aw = Ag + w * (16 * LDST);
  const float* wrp = e_w1 + 256 * 128;
  const float* wep = e_w1 + 257 * 128;
  float a_bv = a_b[0];

  int wg = blockIdx.x * NW + w;
  int s0 = wg * SPAN;
  int s1 = s0 + SPAN; if (s1 > NSTRIPE) s1 = NSTRIPE;

  for (int s = s0; s < s1; ++s) {
    int eg = perm[s * 16 + cix];  // sorted-by-row edge id
    int r = ei[eg], c = ei[NE + eg];
    float ea = eattr[eg];
    float d0 = x[r * 3 + 0] - x[c * 3 + 0];
    float d1 = x[r * 3 + 1] - x[c * 3 + 1];
    float d2 = x[r * 3 + 2] - x[c * 3 + 2];
    float rad = d0 * d0 + d1 * d1 + d2 * d2;
    const bf16_t* par = pa + (size_t)r * 128;
    const bf16_t* pbr = pb + (size_t)c * 128;

    // GEMM1 fused: z1 = silu(pa[r]+pb[c]+rad*w_rad+ea*w_ea) as A-frag; C = z1 @ e_w2
    f32x4 acc[8];
#pragma unroll
    for (int i = 0; i < 8; ++i) acc[i] = (f32x4){0.f, 0.f, 0.f, 0.f};
#pragma unroll
    for (int ks = 0; ks < 4; ++ks) {
      int kk = ks * 32 + koff;
      bf16x8 pa8 = *(const bf16x8*)(par + kk);
      bf16x8 pb8 = *(const bf16x8*)(pbr + kk);
      float4 wr0 = *(const float4*)(wrp + kk);
      float4 wr1 = *(const float4*)(wrp + kk + 4);
      float4 we0 = *(const float4*)(wep + kk);
      float4 we1 = *(const float4*)(wep + kk + 4);
      float wrv[8] = {wr0.x, wr0.y, wr0.z, wr0.w, wr1.x, wr1.y, wr1.z, wr1.w};
      float wev[8] = {we0.x, we0.y, we0.z, we0.w, we1.x, we1.y, we1.z, we1.w};
      bf16x8 af;
#pragma unroll
      for (int j = 0; j < 8; ++j) {
        float z = (float)pa8[j] + (float)pb8[j] + rad * wrv[j] + ea * wev[j];
        af[j] = (bf16_t)siluf(z);
      }
#pragma unroll
      for (int nt = 0; nt < 8; ++nt) {
        bf16x8 b = *(const bf16x8*)(Bs2 + (nt * 256 + (ks * 4 + quad) * 16 + cix) * 8);
        acc[nt] = __builtin_amdgcn_mfma_f32_16x16x32_bf16(af, b, acc[nt], 0, 0, 0);
      }
    }

    // epilogue 1: m = silu(.+b2); att = sigmoid(m.a_w+a_b); m *= att; m -> Aw
    float attp[4] = {0.f, 0.f, 0.f, 0.f};
#pragma unroll
    for (int nt = 0; nt < 8; ++nt) {
      int colg = nt * 16 + cix;
      float b2v = e_b2[colg];
      float awv = a_w[colg];
#pragma unroll
      for (int rix = 0; rix < 4; ++rix) {
        float v = siluf(acc[nt][rix] + b2v);
        acc[nt][rix] = v;
        attp[rix] += v * awv;
      }
    }
    float attv[4];
#pragma unroll
    for (int rix = 0; rix < 4; ++rix) {
      float sv = attp[rix];
      sv += __shfl_xor(sv, 1); sv += __shfl_xor(sv, 2);
      sv += __shfl_xor(sv, 4); sv += __shfl_xor(sv, 8);
      attv[rix] = 1.f / (1.f + __expf(-(sv + a_bv)));
    }
#pragma unroll
    for (int nt = 0; nt < 8; ++nt) {
#pragma unroll
      for (int rix = 0; rix < 4; ++rix) {
        float v = acc[nt][rix] * attv[rix];
        Aw[(quad * 4 + rix) * LDST + nt * 16 + cix] = (bf16_t)v;
      }
    }

    // GEMM2: coord_update = silu(m @ c_w1 + c_b1) . c_w2   (wave-local LDS RAW)
    const bf16_t* Arow = Aw + cix * LDST;
#pragma unroll
    for (int i = 0; i < 8; ++i) acc[i] = (f32x4){0.f, 0.f, 0.f, 0.f};
#pragma unroll
    for (int ks = 0; ks < 4; ++ks) {
      bf16x8 a = *(const bf16x8*)(Arow + ks * 32 + koff);
#pragma unroll
      for (int nt = 0; nt < 8; ++nt) {
        bf16x8 b = *(const bf16x8*)(Bs6 + (nt * 256 + (ks * 4 + quad) * 16 + cix) * 8);
        acc[nt] = __builtin_amdgcn_mfma_f32_16x16x32_bf16(a, b, acc[nt], 0, 0, 0);
      }
    }
    float cup[4] = {0.f, 0.f, 0.f, 0.f};
#pragma unroll
    for (int nt = 0; nt < 8; ++nt) {
      int colg = nt * 16 + cix;
      float cb1v = c_b1[colg];
      float cw2v = c_w2[colg];
#pragma unroll
      for (int rix = 0; rix < 4; ++rix) {
        cup[rix] += siluf(acc[nt][rix] + cb1v) * cw2v;
      }
    }
#pragma unroll
    for (int rix = 0; rix < 4; ++rix) {
      float sv = cup[rix];
      sv += __shfl_xor(sv, 1); sv += __shfl_xor(sv, 2);
      sv += __shfl_xor(sv, 4); sv += __shfl_xor(sv, 8);
      cup[rix] = sv;  // all 16 lanes of the quad hold edge (quad*4+rix)'s scalar
    }

    // merged coord atomics: segmented by row runs (wave-uniform boundaries)
    {
      float c0 = 0.f, c1 = 0.f, c2 = 0.f;
#pragma unroll
      for (int e = 0; e < 16; ++e) {
        float cue = __shfl(cup[e & 3], (e >> 2) * 16);
        float dd0 = __shfl(d0, e), dd1 = __shfl(d1, e), dd2 = __shfl(d2, e);
        int rowe = __shfl(r, e);
        int rown = e < 15 ? __shfl(r, e + 1) : -1;
        c0 += dd0 * cue; c1 += dd1 * cue; c2 += dd2 * cue;
        if (rowe != rown) {
          if (lane == 0) {
            atomicAdd(&coord_agg[rowe * 3 + 0], c0);
            atomicAdd(&coord_agg[rowe * 3 + 1], c1);
            atomicAdd(&coord_agg[rowe * 3 + 2], c2);
          }
          c0 = c1 = c2 = 0.f;
        }
      }
    }

    // merged agg scatter: lane handles cols (2*lane, 2*lane+1); run-boundary atomics
    {
      int col = 2 * lane;
      float sa = 0.f, sb = 0.f;
#pragma unroll
      for (int e = 0; e < 16; ++e) {
        unsigned u = *(const unsigned*)(Aw + e * LDST + col);
        sa += __uint_as_float(u << 16);
        sb += __uint_as_float(u & 0xffff0000u);
        int rowe = __shfl(r, e);
        int rown = e < 15 ? __shfl(r, e + 1) : -1;
        if (rowe != rown) {
          atomicAdd(&agg[(size_t)rowe * 128 + col], sa);
          atomicAdd(&agg[(size_t)rowe * 128 + col + 1], sb);
          sa = sb = 0.f;
        }
      }
    }
  }
}

// ---- node kernel (in-place on d_out) ----
__global__ __launch_bounds__(256) void node_k(
    const float* __restrict__ h, const float* __restrict__ x,
    const bf16_t* __restrict__ wt, const float* __restrict__ n_b1,
    const float* __restrict__ n_b2, const int* __restrict__ deg,
    float* __restrict__ out) {
  __shared__ __align__(16) bf16_t Asb[64 * LDST];
  __shared__ __align__(16) bf16_t Bsb[128 * LDST];
  int t = threadIdx.x;
  int node0 = blockIdx.x * 64;
  const float* agg = out;
  float* xout = out + (size_t)NN * 128;

  if (t < 192) {
    int node = node0 + t / 3;
    int d = t - (t / 3) * 3;
    if (node < NN) {
      int dv = deg[node];
      float denom = dv > 1 ? (float)dv : 1.f;
      float xo = x[node * 3 + d] + xout[node * 3 + d] / denom;
      xout[node * 3 + d] = xo;
    }
  }

  for (int i = t; i < 1024; i += 256) {
    int rowl = i >> 4, cc = i & 15;
    int node = node0 + rowl; if (node >= NN) node = NN - 1;
    const float4* p = (const float4*)(h + (size_t)node * 128 + cc * 8);
    *(bf16x8*)(Asb + rowl * LDST + cc * 8) = cvt8(p[0], p[1]);
  }
  load_B(Bsb, wt + 3 * 16384, t);  // n_w1a_t
  __syncthreads();

  int lane = t & 63, w = t >> 6;
  int m0 = w * 16, quad = lane >> 4, cix = lane & 15, koff = quad * 8;
  const bf16_t* Arow = Asb + (m0 + cix) * LDST;
  const bf16_t* Bcol = Bsb + cix * LDST;

  f32x4 acc[8];
#pragma unroll
  for (int i = 0; i < 8; ++i) acc[i] = (f32x4){0.f, 0.f, 0.f, 0.f};
  gemm_stripe(Arow, Bcol, koff, acc);  // h @ n_w1a

  __syncthreads();

  for (int i = t; i < 1024; i += 256) {
    int rowl = i >> 4, cc = i & 15;
    int node = node0 + rowl; if (node >= NN) node = NN - 1;
    const float4* p = (const float4*)(agg + (size_t)node * 128 + cc * 8);
    *(bf16x8*)(Asb + rowl * LDST + cc * 8) = cvt8(p[0], p[1]);
  }
  load_B(Bsb, wt + 4 * 16384, t);  // n_w1b_t
  __syncthreads();
  gemm_stripe(Arow, Bcol, koff, acc);  // += agg @ n_w1b

#pragma unroll
  for (int nt = 0; nt < 8; ++nt) {
    int colg = nt * 16 + cix;
    float b1v = n_b1[colg];
#pragma unroll
    for (int rix = 0; rix < 4; ++rix) {
      float u = siluf(acc[nt][rix] + b1v);
      Asb[(m0 + quad * 4 + rix) * LDST + colg] = (bf16_t)u;
    }
  }
  __syncthreads();
  load_B(Bsb, wt + 5 * 16384, t);  // n_w2t
  __syncthreads();

#pragma unroll
  for (int i = 0; i < 8; ++i) acc[i] = (f32x4){0.f, 0.f, 0.f, 0.f};
  gemm_stripe(Arow, Bcol, koff, acc);  // u @ n_w2

#pragma unroll
  for (int nt = 0; nt < 8; ++nt) {
    int colg = nt * 16 + cix;
    float b2v = n_b2[colg];
#pragma unroll
    for (int rix = 0; rix < 4; ++rix) {
      int node = node0 + m0 + quad * 4 + rix;
      if (node < NN) {
        float ho = h[(size_t)node * 128 + colg] + acc[nt][rix] + b2v;
        out[(size_t)node * 128 + colg] = ho;
      }
    }
  }
}

extern "C" void kernel_launch(void* const* d_in, const int* in_sizes, int n_in,
                              void* d_out, int out_size, void* d_ws, size_t ws_size,
                              hipStream_t stream) {
  const float* h = (const float*)d_in[0];
  const float* x = (const float*)d_in[1];
  const int* ei = (const int*)d_in[2];
  const float* eattr = (const float*)d_in[3];
  const float* e_w1 = (const float*)d_in[4];
  const float* e_b1 = (const float*)d_in[5];
  const float* e_w2 = (const float*)d_in[6];
  const float* e_b2 = (const float*)d_in[7];
  const float* n_w1 = (const float*)d_in[8];
  const float* n_b1 = (const float*)d_in[9];
  const float* n_w2 = (const float*)d_in[10];
  const float* n_b2 = (const float*)d_in[11];
  const float* c_w1 = (const float*)d_in[12];
  const float* c_b1 = (const float*)d_in[13];
  const float* c_w2 = (const float*)d_in[14];
  const float* a_w = (const float*)d_in[15];
  const float* a_b = (const float*)d_in[16];

  float* outp = (float*)d_out;
  float* agg = outp;                           // N*128 f32 (h_out region)
  float* coord_agg = outp + (size_t)NN * 128;  // N*3 f32 (x_out region)

  // ws layout (total ~29.43 MB):
  //   pa 12.8MB | pb 12.8MB | wt 229KB | deg 200KB | curs 200KB | bsum 256B | perm 3.2MB
  char* ws = (char*)d_ws;
  bf16_t* pa = (bf16_t*)(ws + 0);
  bf16_t* pb = (bf16_t*)(ws + 12800000);
  bf16_t* wt = (bf16_t*)(ws + 25600000);   // 229,376 B
  int* deg = (int*)(ws + 25830400);        // 200,000 B
  int* curs = (int*)(ws + 26030464);       // 200,000 B
  int* bsum = (int*)(ws + 26230528);       // 49*4 B
  int* perm = (int*)(ws + 26230784);       // 3,200,000 B -> ends 29,430,784

  const int NB = (NN + 1023) / 1024;  // 49

  hipMemsetAsync(d_out, 0, (size_t)(NN * 131) * 4, stream);
  hipMemsetAsync((void*)deg, 0, 200000, stream);
  transpose_k<<<7, 256, 0, stream>>>(e_w1, e_w2, n_w1, n_w2, c_w1, wt);
  prep_k<<<(NN + 63) / 64, 256, 0, stream>>>(h, wt, e_b1, pa, pb);
  hist_k<<<(NE + 255) / 256, 256, 0, stream>>>(ei, deg);
  scan1_k<<<NB, 1024, 0, stream>>>(deg, curs, bsum);
  scan2_k<<<1, 64, 0, stream>>>(bsum, NB);
  scan3_k<<<NB, 1024, 0, stream>>>(curs, bsum);
  place_k<<<(NE + 255) / 256, 256, 0, stream>>>(ei, curs, perm);
  edge_k<<<EGRID, 1024, 0, stream>>>(pa, pb, ei, perm, eattr, x, wt, e_w1, e_b2,
                                     c_b1, c_w2, a_w, a_b, agg, coord_agg);
  node_k<<<(NN + 63) / 64, 256, 0, stream>>>(h, x, wt, n_b1, n_b2, deg, outp);
}

// Round 9
// 527.912 us; speedup vs baseline: 1.6070x; 1.1495x over previous
//
#include <hip/hip_runtime.h>

// EGNN layer (round 9): packed sorted edge records + fast silu + run carry.
//  - Round-8 post-mortem: FETCH still ~700MB = random 4B ei/eattr/perm loads
//    amplified to cache lines; VALU 58% dominated by precise f32 division in
//    silu/sigmoid (~96/lane/stripe).
//  - place_k writes int2{row*50000+col, ea_bits} at the sorted slot (same
//    scattered-line cost as perm was); edge_k reads ONE coalesced 8B record
//    per edge -> no random index/attr reads.
//  - silu/sigmoid use v_rcp_f32 (__builtin_amdgcn_rcpf): ~6 VALU vs ~14.
//  - agg/coord accumulators carried across stripes per wave; flush on row
//    change only (atomic dwords 12.8M -> ~7M).
//  - Structure else per round 8: counting sort, zero-barrier persistent edge_k,
//    LDS-resident weights (MFMA-chunk layout), per-wave m stripe.

#define NN 50000
#define NE 800000
#define LDST 136
#define NW 16
#define NSTRIPE (NE / 16)
#define EGRID 256
#define SPAN ((NSTRIPE + EGRID * NW - 1) / (EGRID * NW))  // 13

typedef __bf16 bf16_t;
typedef __bf16 bf16x8 __attribute__((ext_vector_type(8)));
typedef float f32x4 __attribute__((ext_vector_type(4)));

__device__ __forceinline__ float fsilu(float z) {
  return z * __builtin_amdgcn_rcpf(1.f + __expf(-z));
}
__device__ __forceinline__ float fsigm(float z) {
  return __builtin_amdgcn_rcpf(1.f + __expf(-z));
}

__device__ __forceinline__ void gemm_stripe(const bf16_t* Arow, const bf16_t* Bcol,
                                            int koff, f32x4 acc[8]) {
#pragma unroll
  for (int ks = 0; ks < 4; ++ks) {
    bf16x8 a = *(const bf16x8*)(Arow + ks * 32 + koff);
#pragma unroll
    for (int nt = 0; nt < 8; ++nt) {
      bf16x8 b = *(const bf16x8*)(Bcol + nt * 16 * LDST + ks * 32 + koff);
      acc[nt] = __builtin_amdgcn_mfma_f32_16x16x32_bf16(a, b, acc[nt], 0, 0, 0);
    }
  }
}

__device__ __forceinline__ void load_B(bf16_t* Bsb, const bf16_t* __restrict__ src, int t) {
  for (int i = t; i < 2048; i += 256) {
    int n = i >> 4, cc = i & 15;
    *(bf16x8*)(Bsb + n * LDST + cc * 8) = *(const bf16x8*)(src + n * 128 + cc * 8);
  }
}

__device__ __forceinline__ bf16x8 cvt8(float4 u0, float4 u1) {
  bf16x8 v;
  v[0] = (bf16_t)u0.x; v[1] = (bf16_t)u0.y; v[2] = (bf16_t)u0.z; v[3] = (bf16_t)u0.w;
  v[4] = (bf16_t)u1.x; v[5] = (bf16_t)u1.y; v[6] = (bf16_t)u1.z; v[7] = (bf16_t)u1.w;
  return v;
}

// ---- transpose 7 128x128 f32 weight blocks into bf16 wt ([n][k] layout) ----
// slots: 0 W1a_t, 1 W1b_t, 2 e_w2t, 3 n_w1a_t, 4 n_w1b_t, 5 n_w2t, 6 c_w1t
__global__ __launch_bounds__(256) void transpose_k(
    const float* __restrict__ e_w1, const float* __restrict__ e_w2,
    const float* __restrict__ n_w1, const float* __restrict__ n_w2,
    const float* __restrict__ c_w1, bf16_t* __restrict__ wt) {
  int b = blockIdx.x;
  const float* src;
  switch (b) {
    case 0: src = e_w1; break;
    case 1: src = e_w1 + 16384; break;
    case 2: src = e_w2; break;
    case 3: src = n_w1; break;
    case 4: src = n_w1 + 16384; break;
    case 5: src = n_w2; break;
    default: src = c_w1; break;
  }
  bf16_t* dst = wt + b * 16384;
  for (int i = threadIdx.x; i < 16384; i += 256) {
    int k = i >> 7, n = i & 127;
    dst[n * 128 + k] = (bf16_t)src[k * 128 + n];
  }
}

// ---- prep: pa = bf16(h@W1a + e_b1), pb = bf16(h@W1b) ----
__global__ __launch_bounds__(256) void prep_k(
    const float* __restrict__ h, const bf16_t* __restrict__ wt,
    const float* __restrict__ e_b1, bf16_t* __restrict__ pa, bf16_t* __restrict__ pb) {
  __shared__ __align__(16) bf16_t Asb[64 * LDST];
  __shared__ __align__(16) bf16_t Bsb[128 * LDST];
  int t = threadIdx.x;
  int node0 = blockIdx.x * 64;
  for (int i = t; i < 1024; i += 256) {
    int rowl = i >> 4, cc = i & 15;
    int node = node0 + rowl; if (node >= NN) node = NN - 1;
    const float4* p = (const float4*)(h + (size_t)node * 128 + cc * 8);
    *(bf16x8*)(Asb + rowl * LDST + cc * 8) = cvt8(p[0], p[1]);
  }
  int lane = t & 63, w = t >> 6;
  int m0 = w * 16, quad = lane >> 4, cix = lane & 15, koff = quad * 8;
  const bf16_t* Arow = Asb + (m0 + cix) * LDST;
  const bf16_t* Bcol = Bsb + cix * LDST;

  bf16_t* outp[2] = {pa, pb};
#pragma unroll
  for (int p = 0; p < 2; ++p) {
    __syncthreads();
    load_B(Bsb, wt + p * 16384, t);
    __syncthreads();
    f32x4 acc[8];
#pragma unroll
    for (int i = 0; i < 8; ++i) acc[i] = (f32x4){0.f, 0.f, 0.f, 0.f};
    gemm_stripe(Arow, Bcol, koff, acc);
#pragma unroll
    for (int nt = 0; nt < 8; ++nt) {
      int colg = nt * 16 + cix;
      float bv = p == 0 ? e_b1[colg] : 0.f;
#pragma unroll
      for (int rix = 0; rix < 4; ++rix) {
        int node = node0 + m0 + quad * 4 + rix;
        if (node < NN) outp[p][(size_t)node * 128 + colg] = (bf16_t)(acc[nt][rix] + bv);
      }
    }
  }
}

// ---- counting sort by row: hist -> scan (2-level) -> place packed records ----
__global__ __launch_bounds__(256) void hist_k(const int* __restrict__ ei,
                                              int* __restrict__ deg) {
  int e = blockIdx.x * 256 + threadIdx.x;
  if (e < NE) atomicAdd(&deg[ei[e]], 1);
}

__global__ __launch_bounds__(1024) void scan1_k(const int* __restrict__ deg,
                                                int* __restrict__ curs,
                                                int* __restrict__ bsum) {
  __shared__ int sm[1024];
  int t = threadIdx.x;
  int i = blockIdx.x * 1024 + t;
  int v = (i < NN) ? deg[i] : 0;
  sm[t] = v;
  __syncthreads();
  for (int off = 1; off < 1024; off <<= 1) {
    int add = (t >= off) ? sm[t - off] : 0;
    __syncthreads();
    sm[t] += add;
    __syncthreads();
  }
  if (i < NN) curs[i] = sm[t] - v;
  if (t == 1023) bsum[blockIdx.x] = sm[1023];
}

__global__ void scan2_k(int* __restrict__ bsum, int nb) {
  if (threadIdx.x == 0) {
    int acc = 0;
    for (int b = 0; b < nb; ++b) { int v = bsum[b]; bsum[b] = acc; acc += v; }
  }
}

__global__ __launch_bounds__(1024) void scan3_k(int* __restrict__ curs,
                                                const int* __restrict__ bsum) {
  int i = blockIdx.x * 1024 + threadIdx.x;
  if (i < NN) curs[i] += bsum[blockIdx.x];
}

__global__ __launch_bounds__(256) void place_k(const int* __restrict__ ei,
                                               const float* __restrict__ eattr,
                                               int* __restrict__ curs,
                                               int2* __restrict__ rec) {
  int e = blockIdx.x * 256 + threadIdx.x;
  if (e < NE) {
    int row = ei[e];
    int col = ei[NE + e];
    int pos = atomicAdd(&curs[row], 1);
    int2 rv;
    rv.x = (int)((unsigned)row * 50000u + (unsigned)col);
    rv.y = __float_as_int(eattr[e]);
    rec[pos] = rv;
  }
}

// ---- edge kernel: sorted records, contiguous spans, carried-run scatter ----
__global__ __launch_bounds__(1024, 4) void edge_k(
    const bf16_t* __restrict__ pa, const bf16_t* __restrict__ pb,
    const int2* __restrict__ rec, const float* __restrict__ x,
    const bf16_t* __restrict__ wt, const float* __restrict__ e_w1,
    const float* __restrict__ e_b2, const float* __restrict__ c_b1,
    const float* __restrict__ c_w2, const float* __restrict__ a_w,
    const float* __restrict__ a_b, float* __restrict__ agg,
    float* __restrict__ coord_agg) {
  __shared__ __align__(16) bf16_t Bs2[16384];          // e_w2 (MFMA-chunk layout)
  __shared__ __align__(16) bf16_t Bs6[16384];          // c_w1
  __shared__ __align__(16) bf16_t Ag[NW * 16 * LDST];  // per-wave m stripes

  int t = threadIdx.x;
  for (int cch = t; cch < 2048; cch += 1024) {
    int nt = cch >> 8, rem = cch & 255, kc = rem >> 4, ci = rem & 15;
    int n = nt * 16 + ci;
    *(bf16x8*)(Bs2 + cch * 8) = *(const bf16x8*)(wt + 2 * 16384 + n * 128 + kc * 8);
    *(bf16x8*)(Bs6 + cch * 8) = *(const bf16x8*)(wt + 6 * 16384 + n * 128 + kc * 8);
  }
  __syncthreads();  // the only barrier

  int lane = t & 63, w = t >> 6;
  int quad = lane >> 4, cix = lane & 15, koff = quad * 8;
  bf16_t* Aw = Ag + w * (16 * LDST);
  const float* wrp = e_w1 + 256 * 128;
  const float* wep = e_w1 + 257 * 128;
  float a_bv = a_b[0];

  int wg = blockIdx.x * NW + w;
  int s0 = wg * SPAN;
  int s1 = s0 + SPAN; if (s1 > NSTRIPE) s1 = NSTRIPE;

  // carried run state (wave-uniform currow; per-lane col sums)
  int currow = -1;
  int col = 2 * lane;
  float sa = 0.f, sb = 0.f, c0 = 0.f, c1 = 0.f, c2 = 0.f;

  for (int s = s0; s < s1; ++s) {
    int2 rv = rec[s * 16 + cix];
    unsigned rc = (unsigned)rv.x;
    int r = (int)(rc / 50000u);
    int c = (int)(rc - (unsigned)r * 50000u);
    float ea = __int_as_float(rv.y);
    float d0 = x[r * 3 + 0] - x[c * 3 + 0];
    float d1 = x[r * 3 + 1] - x[c * 3 + 1];
    float d2 = x[r * 3 + 2] - x[c * 3 + 2];
    float rad = d0 * d0 + d1 * d1 + d2 * d2;
    const bf16_t* par = pa + (size_t)r * 128;
    const bf16_t* pbr = pb + (size_t)c * 128;

    // GEMM1 fused: z1 = silu(pa[r]+pb[c]+rad*w_rad+ea*w_ea) as A-frag; C = z1 @ e_w2
    f32x4 acc[8];
#pragma unroll
    for (int i = 0; i < 8; ++i) acc[i] = (f32x4){0.f, 0.f, 0.f, 0.f};
#pragma unroll
    for (int ks = 0; ks < 4; ++ks) {
      int kk = ks * 32 + koff;
      bf16x8 pa8 = *(const bf16x8*)(par + kk);
      bf16x8 pb8 = *(const bf16x8*)(pbr + kk);
      float4 wr0 = *(const float4*)(wrp + kk);
      float4 wr1 = *(const float4*)(wrp + kk + 4);
      float4 we0 = *(const float4*)(wep + kk);
      float4 we1 = *(const float4*)(wep + kk + 4);
      float wrv[8] = {wr0.x, wr0.y, wr0.z, wr0.w, wr1.x, wr1.y, wr1.z, wr1.w};
      float wev[8] = {we0.x, we0.y, we0.z, we0.w, we1.x, we1.y, we1.z, we1.w};
      bf16x8 af;
#pragma unroll
      for (int j = 0; j < 8; ++j) {
        float z = (float)pa8[j] + (float)pb8[j] + rad * wrv[j] + ea * wev[j];
        af[j] = (bf16_t)fsilu(z);
      }
#pragma unroll
      for (int nt = 0; nt < 8; ++nt) {
        bf16x8 b = *(const bf16x8*)(Bs2 + (nt * 256 + (ks * 4 + quad) * 16 + cix) * 8);
        acc[nt] = __builtin_amdgcn_mfma_f32_16x16x32_bf16(af, b, acc[nt], 0, 0, 0);
      }
    }

    // epilogue 1: m = silu(.+b2); att = sigmoid(m.a_w+a_b); m *= att; m -> Aw
    float attp[4] = {0.f, 0.f, 0.f, 0.f};
#pragma unroll
    for (int nt = 0; nt < 8; ++nt) {
      int colg = nt * 16 + cix;
      float b2v = e_b2[colg];
      float awv = a_w[colg];
#pragma unroll
      for (int rix = 0; rix < 4; ++rix) {
        float v = fsilu(acc[nt][rix] + b2v);
        acc[nt][rix] = v;
        attp[rix] += v * awv;
      }
    }
    float attv[4];
#pragma unroll
    for (int rix = 0; rix < 4; ++rix) {
      float sv = attp[rix];
      sv += __shfl_xor(sv, 1); sv += __shfl_xor(sv, 2);
      sv += __shfl_xor(sv, 4); sv += __shfl_xor(sv, 8);
      attv[rix] = fsigm(sv + a_bv);
    }
#pragma unroll
    for (int nt = 0; nt < 8; ++nt) {
#pragma unroll
      for (int rix = 0; rix < 4; ++rix) {
        float v = acc[nt][rix] * attv[rix];
        Aw[(quad * 4 + rix) * LDST + nt * 16 + cix] = (bf16_t)v;
      }
    }

    // GEMM2: coord_update = silu(m @ c_w1 + c_b1) . c_w2   (wave-local LDS RAW)
    const bf16_t* Arow = Aw + cix * LDST;
#pragma unroll
    for (int i = 0; i < 8; ++i) acc[i] = (f32x4){0.f, 0.f, 0.f, 0.f};
#pragma unroll
    for (int ks = 0; ks < 4; ++ks) {
      bf16x8 a = *(const bf16x8*)(Arow + ks * 32 + koff);
#pragma unroll
      for (int nt = 0; nt < 8; ++nt) {
        bf16x8 b = *(const bf16x8*)(Bs6 + (nt * 256 + (ks * 4 + quad) * 16 + cix) * 8);
        acc[nt] = __builtin_amdgcn_mfma_f32_16x16x32_bf16(a, b, acc[nt], 0, 0, 0);
      }
    }
    float cup[4] = {0.f, 0.f, 0.f, 0.f};
#pragma unroll
    for (int nt = 0; nt < 8; ++nt) {
      int colg = nt * 16 + cix;
      float cb1v = c_b1[colg];
      float cw2v = c_w2[colg];
#pragma unroll
      for (int rix = 0; rix < 4; ++rix) {
        cup[rix] += fsilu(acc[nt][rix] + cb1v) * cw2v;
      }
    }
#pragma unroll
    for (int rix = 0; rix < 4; ++rix) {
      float sv = cup[rix];
      sv += __shfl_xor(sv, 1); sv += __shfl_xor(sv, 2);
      sv += __shfl_xor(sv, 4); sv += __shfl_xor(sv, 8);
      cup[rix] = sv;  // all 16 lanes of the quad hold that edge's scalar
    }

    // carried-run merge: flush only on row change (runs span stripes)
#pragma unroll
    for (int e = 0; e < 16; ++e) {
      int rowe = __shfl(r, e);
      if (rowe != currow) {
        if (currow >= 0) {
          atomicAdd(&agg[(size_t)currow * 128 + col], sa);
          atomicAdd(&agg[(size_t)currow * 128 + col + 1], sb);
          if (lane == 0) {
            atomicAdd(&coord_agg[currow * 3 + 0], c0);
            atomicAdd(&coord_agg[currow * 3 + 1], c1);
            atomicAdd(&coord_agg[currow * 3 + 2], c2);
          }
        }
        sa = sb = c0 = c1 = c2 = 0.f;
        currow = rowe;
      }
      float cue = __shfl(cup[e & 3], (e >> 2) * 16);
      float dd0 = __shfl(d0, e), dd1 = __shfl(d1, e), dd2 = __shfl(d2, e);
      c0 += dd0 * cue; c1 += dd1 * cue; c2 += dd2 * cue;
      unsigned u = *(const unsigned*)(Aw + e * LDST + col);
      sa += __uint_as_float(u << 16);
      sb += __uint_as_float(u & 0xffff0000u);
    }
  }

  // final flush
  if (currow >= 0) {
    atomicAdd(&agg[(size_t)currow * 128 + col], sa);
    atomicAdd(&agg[(size_t)currow * 128 + col + 1], sb);
    if (lane == 0) {
      atomicAdd(&coord_agg[currow * 3 + 0], c0);
      atomicAdd(&coord_agg[currow * 3 + 1], c1);
      atomicAdd(&coord_agg[currow * 3 + 2], c2);
    }
  }
}

// ---- node kernel (in-place on d_out) ----
__global__ __launch_bounds__(256) void node_k(
    const float* __restrict__ h, const float* __restrict__ x,
    const bf16_t* __restrict__ wt, const float* __restrict__ n_b1,
    const float* __restrict__ n_b2, const int* __restrict__ deg,
    float* __restrict__ out) {
  __shared__ __align__(16) bf16_t Asb[64 * LDST];
  __shared__ __align__(16) bf16_t Bsb[128 * LDST];
  int t = threadIdx.x;
  int node0 = blockIdx.x * 64;
  const float* agg = out;
  float* xout = out + (size_t)NN * 128;

  if (t < 192) {
    int node = node0 + t / 3;
    int d = t - (t / 3) * 3;
    if (node < NN) {
      int dv = deg[node];
      float denom = dv > 1 ? (float)dv : 1.f;
      float xo = x[node * 3 + d] + xout[node * 3 + d] / denom;
      xout[node * 3 + d] = xo;
    }
  }

  for (int i = t; i < 1024; i += 256) {
    int rowl = i >> 4, cc = i & 15;
    int node = node0 + rowl; if (node >= NN) node = NN - 1;
    const float4* p = (const float4*)(h + (size_t)node * 128 + cc * 8);
    *(bf16x8*)(Asb + rowl * LDST + cc * 8) = cvt8(p[0], p[1]);
  }
  load_B(Bsb, wt + 3 * 16384, t);  // n_w1a_t
  __syncthreads();

  int lane = t & 63, w = t >> 6;
  int m0 = w * 16, quad = lane >> 4, cix = lane & 15, koff = quad * 8;
  const bf16_t* Arow = Asb + (m0 + cix) * LDST;
  const bf16_t* Bcol = Bsb + cix * LDST;

  f32x4 acc[8];
#pragma unroll
  for (int i = 0; i < 8; ++i) acc[i] = (f32x4){0.f, 0.f, 0.f, 0.f};
  gemm_stripe(Arow, Bcol, koff, acc);  // h @ n_w1a

  __syncthreads();

  for (int i = t; i < 1024; i += 256) {
    int rowl = i >> 4, cc = i & 15;
    int node = node0 + rowl; if (node >= NN) node = NN - 1;
    const float4* p = (const float4*)(agg + (size_t)node * 128 + cc * 8);
    *(bf16x8*)(Asb + rowl * LDST + cc * 8) = cvt8(p[0], p[1]);
  }
  load_B(Bsb, wt + 4 * 16384, t);  // n_w1b_t
  __syncthreads();
  gemm_stripe(Arow, Bcol, koff, acc);  // += agg @ n_w1b

#pragma unroll
  for (int nt = 0; nt < 8; ++nt) {
    int colg = nt * 16 + cix;
    float b1v = n_b1[colg];
#pragma unroll
    for (int rix = 0; rix < 4; ++rix) {
      float u = fsilu(acc[nt][rix] + b1v);
      Asb[(m0 + quad * 4 + rix) * LDST + colg] = (bf16_t)u;
    }
  }
  __syncthreads();
  load_B(Bsb, wt + 5 * 16384, t);  // n_w2t
  __syncthreads();

#pragma unroll
  for (int i = 0; i < 8; ++i) acc[i] = (f32x4){0.f, 0.f, 0.f, 0.f};
  gemm_stripe(Arow, Bcol, koff, acc);  // u @ n_w2

#pragma unroll
  for (int nt = 0; nt < 8; ++nt) {
    int colg = nt * 16 + cix;
    float b2v = n_b2[colg];
#pragma unroll
    for (int rix = 0; rix < 4; ++rix) {
      int node = node0 + m0 + quad * 4 + rix;
      if (node < NN) {
        float ho = h[(size_t)node * 128 + colg] + acc[nt][rix] + b2v;
        out[(size_t)node * 128 + colg] = ho;
      }
    }
  }
}

extern "C" void kernel_launch(void* const* d_in, const int* in_sizes, int n_in,
                              void* d_out, int out_size, void* d_ws, size_t ws_size,
                              hipStream_t stream) {
  const float* h = (const float*)d_in[0];
  const float* x = (const float*)d_in[1];
  const int* ei = (const int*)d_in[2];
  const float* eattr = (const float*)d_in[3];
  const float* e_w1 = (const float*)d_in[4];
  const float* e_b1 = (const float*)d_in[5];
  const float* e_w2 = (const float*)d_in[6];
  const float* e_b2 = (const float*)d_in[7];
  const float* n_w1 = (const float*)d_in[8];
  const float* n_b1 = (const float*)d_in[9];
  const float* n_w2 = (const float*)d_in[10];
  const float* n_b2 = (const float*)d_in[11];
  const float* c_w1 = (const float*)d_in[12];
  const float* c_b1 = (const float*)d_in[13];
  const float* c_w2 = (const float*)d_in[14];
  const float* a_w = (const float*)d_in[15];
  const float* a_b = (const float*)d_in[16];

  float* outp = (float*)d_out;
  float* agg = outp;                           // N*128 f32 (h_out region)
  float* coord_agg = outp + (size_t)NN * 128;  // N*3 f32 (x_out region)

  // ws layout (total ~32.63 MB):
  //   pa 12.8MB | pb 12.8MB | wt 229KB | deg 200KB | curs 200KB | bsum 256B | rec 6.4MB
  char* ws = (char*)d_ws;
  bf16_t* pa = (bf16_t*)(ws + 0);
  bf16_t* pb = (bf16_t*)(ws + 12800000);
  bf16_t* wt = (bf16_t*)(ws + 25600000);   // 229,376 B
  int* deg = (int*)(ws + 25830400);        // 200,000 B
  int* curs = (int*)(ws + 26030464);       // 200,000 B
  int* bsum = (int*)(ws + 26230528);       // 256 B
  int2* rec = (int2*)(ws + 26230784);      // 6,400,000 B -> ends 32,630,784

  const int NB = (NN + 1023) / 1024;  // 49

  hipMemsetAsync(d_out, 0, (size_t)(NN * 131) * 4, stream);
  hipMemsetAsync((void*)deg, 0, 200000, stream);
  transpose_k<<<7, 256, 0, stream>>>(e_w1, e_w2, n_w1, n_w2, c_w1, wt);
  prep_k<<<(NN + 63) / 64, 256, 0, stream>>>(h, wt, e_b1, pa, pb);
  hist_k<<<(NE + 255) / 256, 256, 0, stream>>>(ei, deg);
  scan1_k<<<NB, 1024, 0, stream>>>(deg, curs, bsum);
  scan2_k<<<1, 64, 0, stream>>>(bsum, NB);
  scan3_k<<<NB, 1024, 0, stream>>>(curs, bsum);
  place_k<<<(NE + 255) / 256, 256, 0, stream>>>(ei, eattr, curs, rec);
  edge_k<<<EGRID, 1024, 0, stream>>>(pa, pb, rec, x, wt, e_w1, e_b2, c_b1, c_w2,
                                     a_w, a_b, agg, coord_agg);
  node_k<<<(NN + 63) / 64, 256, 0, stream>>>(h, x, wt, n_b1, n_b2, deg, outp);
}